// Round 2
// baseline (32308.875 us; speedup 1.0000x reference)
//
#include <hip/hip_runtime.h>

// AdaDecoder — persistent kernel with software grid barrier (round 8).
// R7 post-mortem: hipLaunchCooperativeKernel silently failed under the harness's
// stream capture (output stayed zero). Same persistent structure, but now a plain
// <<<240,256>>> launch + workspace-resident sense-free monotonic barrier:
//   arrive: __threadfence (release, wb L2) + agent-scope atomicAdd
//   wait:   relaxed agent-scope poll + s_sleep, one acquire fence on exit
// 240 blocks <= 256 CUs, 1 block/CU always fits -> co-residency guaranteed.
// Phases per step t:
//  A: gates GEMM (t) + logits GEMM (t-1)            [MFMA, 946 wave-jobs]
//  B: log-softmax(t-1) (blocks 0..31) || LSTM pointwise (blocks 32..63)
//  C: [fr_pre|h] @ diag(Wfr,Who) + relu/tanh -> AB2 [MFMA, 64 wave-jobs]
//  D: [fr|hol] @ [Wfre|Whoe|Watt|Watt] -> V4 fp32   [MFMA, 128 wave-jobs]
//  EF: scores + softmax + vis + out_h -> zb         [blocks 0..31]

typedef unsigned short u16;
typedef __attribute__((ext_vector_type(8))) short s8;
typedef __attribute__((ext_vector_type(4))) float f4;

#define TT 160
#define NBLK 240

// ---------------- ws layout (bytes) ----------------
static constexpr size_t oZB   = 0;              // u16 zb[32][1280]  (xt|out_prev|h)
static constexpr size_t oC    = 81920;          // float c[2][32][512]
static constexpr size_t oFLAG = 212992;         // int dtype flag (1 = fp32 inputs)
static constexpr size_t oBAR  = 213504;         // unsigned barrier counter (own line)
static constexpr size_t ZERO_END = 217088;
static constexpr size_t oWT1  = 217088;         // u16 [2560][1280]  gates/n5 W^T
static constexpr size_t oWT2  = 6770688;        // u16 [5008][512]   Wlog^T (padded)
static constexpr size_t oWT3  = 11898880;       // u16 [1024][512]   [Wce^T | Watt^T]
static constexpr size_t oBG   = 12947456;       // float bg[2560]
static constexpr size_t oXE   = 12957696;       // u16 xemb[160][32][256]
static constexpr size_t oCE   = 15579136;       // u16 CE[32][256][512]
static constexpr size_t oCW   = 23967744;       // u16 CW[32][256][512]
static constexpr size_t oGP0  = 32356352;       // float gp0[32][2560]
static constexpr size_t oGP1  = 32684032;
static constexpr size_t oLP0  = 33011712;       // float lp0[32][5008]
static constexpr size_t oLP1  = 33652736;       // end 34293760
static constexpr size_t oAB1  = 34293760;       // u16 [32][1024]  [fr_pre|h]
static constexpr size_t oAB2  = 34359296;       // u16 [32][1024]  [fr|hol]
static constexpr size_t oV4   = 34424832;       // float [32][2048] [fre|hoe|frW|holW]
static constexpr size_t oW45T = 34686976;       // u16 [1024][1024] diag(Wfr^T,Who^T)
static constexpr size_t oW6T  = 36784128;       // u16 [2048][1024] big B^T
                                                // end 40978432

__device__ __forceinline__ float b2f(u16 u){ return __uint_as_float(((unsigned)u) << 16); }
__device__ __forceinline__ u16 f2b(float f){
  unsigned x = __float_as_uint(f);
  return (u16)((x + 0x7fffu + ((x >> 16) & 1u)) >> 16);
}
__device__ __forceinline__ float sigm(float x){ return 1.0f/(1.0f + __expf(-x)); }
__device__ __forceinline__ float tanhp(float x){ return 1.0f - 2.0f/(__expf(2.0f*x) + 1.0f); }
__device__ __forceinline__ u16 rdb(const void* p, size_t i, int f){
  return f ? f2b(((const float*)p)[i]) : ((const u16*)p)[i];
}
__device__ __forceinline__ float rdf(const void* p, size_t i, int f){
  return f ? ((const float*)p)[i] : b2f(((const u16*)p)[i]);
}

// Software grid barrier: monotonic counter, no reset. gen is per-block local.
// Release: __threadfence() (agent scope -> L2 writeback) + agent atomicAdd.
// Wait: relaxed agent polls (no per-poll invalidate) + acquire fence on exit.
__device__ __forceinline__ void gbar(unsigned* cnt, unsigned& gen){
  __syncthreads();
  if (threadIdx.x == 0){
    gen += NBLK;
    __threadfence();
    __hip_atomic_fetch_add(cnt, 1u, __ATOMIC_RELEASE, __HIP_MEMORY_SCOPE_AGENT);
    while (__hip_atomic_load(cnt, __ATOMIC_RELAXED, __HIP_MEMORY_SCOPE_AGENT) < gen)
      __builtin_amdgcn_s_sleep(1);
    __threadfence();
  }
  __syncthreads();
}

// ---------------- probe: detect input dtype ----------------
__global__ void probek(const u16* __restrict__ a, int* flag){
  __shared__ int s[256];
  int t = threadIdx.x;
  float v = fabsf(b2f(a[t]));
  s[t] = (v < 64.0f) ? 0 : 1;
  __syncthreads();
  for (int o = 128; o; o >>= 1){ if (t < o) s[t] += s[t+o]; __syncthreads(); }
  if (t == 0) *flag = (s[0] > 0) ? 1 : 0;
}

// ---------------- preamble kernels ----------------
// dst[n*stride + k] = src[k*C + n]
__global__ void tposek(const void* __restrict__ src, u16* __restrict__ dst,
                       int R, int C, int stride, const int* __restrict__ flag){
  __shared__ u16 tl[32][33];
  const int f = *flag;
  int nt = blockIdx.x*32, kt = blockIdx.y*32;
  int tx = threadIdx.x & 31, ty = threadIdx.x >> 5;
  #pragma unroll
  for (int i = 0; i < 4; i++){
    int k = kt + ty + i*8, n = nt + tx;
    tl[ty + i*8][tx] = (k < R && n < C) ? rdb(src, (size_t)k*C + n, f) : (u16)0;
  }
  __syncthreads();
  #pragma unroll
  for (int i = 0; i < 4; i++){
    int n = nt + ty + i*8, k = kt + tx;
    if (n < C && k < R) dst[(size_t)n*stride + k] = tl[tx][ty + i*8];
  }
}

__global__ void biask(const void* bih, const void* bhh, const void* bi2h, const void* bh2h,
                      float* bg, const int* __restrict__ flag){
  const int f = *flag;
  int n = blockIdx.x*256 + threadIdx.x;
  if (n >= 2560) return;
  if (n < 2048) bg[n] = rdf(bih, n, f) + rdf(bhh, n, f);
  else { int j = n - 2048; bg[n] = rdf(bi2h, j, f) + rdf(bh2h, j, f); }
}

__global__ void xembk(const int* __restrict__ seq, const void* __restrict__ embed,
                      u16* __restrict__ xe, u16* __restrict__ zb,
                      const int* __restrict__ flag){
  const int f = *flag;
  int t = blockIdx.x, b = blockIdx.y, e = threadIdx.x;
  int idx = seq[b*161 + t];
  u16 v = rdb(embed, (size_t)idx*256 + e, f);
  xe[((size_t)t*32 + b)*256 + e] = v;
  if (t == 0) zb[(size_t)b*1280 + e] = v;
}

// CE = relu(cnn@Wce + bce), CW = cnn@Watt   (M=8192, N=1024, K=512)
__global__ __launch_bounds__(256) void ctxgemm(const void* __restrict__ A,
                                               const u16* __restrict__ WT3,
                                               const void* __restrict__ bce,
                                               u16* __restrict__ CE, u16* __restrict__ CW,
                                               const int* __restrict__ flag){
  const int f = *flag;
  int wave = threadIdx.x >> 6, lane = threadIdx.x & 63;
  int job = blockIdx.x*4 + wave;
  int mq = job >> 4, nq = job & 15;
  int m0 = mq*64, n0 = nq*64;
  int lr = lane & 15, lq = lane >> 4;
  f4 acc[4][4] = {};
  for (int ks = 0; ks < 16; ks++){
    int k0 = ks*32 + lq*8;
    s8 a[4], b[4];
    #pragma unroll
    for (int mt = 0; mt < 4; mt++){
      size_t base = (size_t)(m0 + mt*16 + lr)*512 + k0;
      if (f){
        const float4* ap = (const float4*)((const float*)A + base);
        float4 q0 = ap[0], q1 = ap[1];
        union { u16 u[8]; s8 v; } pk;
        pk.u[0]=f2b(q0.x); pk.u[1]=f2b(q0.y); pk.u[2]=f2b(q0.z); pk.u[3]=f2b(q0.w);
        pk.u[4]=f2b(q1.x); pk.u[5]=f2b(q1.y); pk.u[6]=f2b(q1.z); pk.u[7]=f2b(q1.w);
        a[mt] = pk.v;
      } else {
        a[mt] = *(const s8*)((const u16*)A + base);
      }
    }
    #pragma unroll
    for (int nt = 0; nt < 4; nt++) b[nt] = *(const s8*)(WT3 + (size_t)(n0 + nt*16 + lr)*512 + k0);
    #pragma unroll
    for (int mt = 0; mt < 4; mt++)
      #pragma unroll
      for (int nt = 0; nt < 4; nt++)
        acc[mt][nt] = __builtin_amdgcn_mfma_f32_16x16x32_bf16(a[mt], b[nt], acc[mt][nt], 0, 0, 0);
  }
  #pragma unroll
  for (int mt = 0; mt < 4; mt++)
    #pragma unroll
    for (int nt = 0; nt < 4; nt++)
      #pragma unroll
      for (int r = 0; r < 4; r++){
        int row = m0 + mt*16 + lq*4 + r;
        int col = n0 + nt*16 + lr;
        float d = acc[mt][nt][r];
        if (col < 512){ d += rdf(bce, col, f); d = d > 0.f ? d : 0.f; CE[(size_t)row*512 + col] = f2b(d); }
        else CW[(size_t)row*512 + (col - 512)] = f2b(d);
      }
}

// ---------------- persistent step kernel ----------------
struct DP {
  const void *bfr, *bfre, *bho, *bhoe, *Wa, *batt, *blog;
  const u16 *WT1, *WT2, *xe, *CE, *CW, *w45, *w6;
  const float *bg;
  const int *flag;
  u16 *zb, *ab1, *ab2; float *cbuf, *v4;
  float *gp0, *gp1, *lp0, *lp1;
  unsigned *bar;
  void *out;
};

// NBLK blocks x 256 threads, persistent. Whole t-loop inside.
__global__ __launch_bounds__(256) void loopk(DP p){
  const int blk = blockIdx.x;
  const int tid = threadIdx.x, lane = tid & 63, wv = tid >> 6;
  const int lr = lane & 15, lq = lane >> 4;
  const int f = *p.flag;
  unsigned gen = 0;

  __shared__ float sFRE[512], sHOE[512], sWa[512], sP[257], sRED[256], sV[4][512];

  for (int t = 0; t <= TT; ++t){
    // ---------------- phase A: gates GEMM (t) + logits GEMM (t-1) ----------------
    {
      const int gwave = blk*4 + wv;
      if (t < TT && gwave < 320){
        const int nt = gwave >> 1, kh = gwave & 1;
        const u16* Bp = p.WT1 + (size_t)(nt*16 + lr)*1280 + kh*640 + lq*8;
        const u16* Ap = p.zb + (size_t)lr*1280 + kh*640 + lq*8;
        f4 a0 = {0,0,0,0}, a1 = {0,0,0,0};
        #pragma unroll 4
        for (int ks = 0; ks < 20; ++ks){
          s8 fa0 = *(const s8*)(Ap + ks*32);
          s8 fa1 = *(const s8*)(Ap + 16*1280 + ks*32);
          s8 fb  = *(const s8*)(Bp + ks*32);
          a0 = __builtin_amdgcn_mfma_f32_16x16x32_bf16(fa0, fb, a0, 0, 0, 0);
          a1 = __builtin_amdgcn_mfma_f32_16x16x32_bf16(fa1, fb, a1, 0, 0, 0);
        }
        float* gp = kh ? p.gp1 : p.gp0;
        const int col = nt*16 + lr, r0 = lq*4;
        #pragma unroll
        for (int r = 0; r < 4; ++r){
          gp[(size_t)(r0 + r)*2560 + col] = a0[r];
          gp[(size_t)(16 + r0 + r)*2560 + col] = a1[r];
        }
      } else if (t > 0 && gwave >= 320 && gwave < 946){
        const int j = gwave - 320, nt = j >> 1, kh = j & 1;
        const u16* Bp = p.WT2 + (size_t)(nt*16 + lr)*512 + kh*256 + lq*8;
        const u16* Ap = p.zb + 256 + (size_t)lr*1280 + kh*256 + lq*8;
        f4 a0 = {0,0,0,0}, a1 = {0,0,0,0};
        #pragma unroll
        for (int ks = 0; ks < 8; ++ks){
          s8 fa0 = *(const s8*)(Ap + ks*32);
          s8 fa1 = *(const s8*)(Ap + 16*1280 + ks*32);
          s8 fb  = *(const s8*)(Bp + ks*32);
          a0 = __builtin_amdgcn_mfma_f32_16x16x32_bf16(fa0, fb, a0, 0, 0, 0);
          a1 = __builtin_amdgcn_mfma_f32_16x16x32_bf16(fa1, fb, a1, 0, 0, 0);
        }
        float* lp = kh ? p.lp1 : p.lp0;
        const int col = nt*16 + lr, r0 = lq*4;
        #pragma unroll
        for (int r = 0; r < 4; ++r){
          lp[(size_t)(r0 + r)*5008 + col] = a0[r];
          lp[(size_t)(16 + r0 + r)*5008 + col] = a1[r];
        }
      }
    }
    gbar(p.bar, gen);

    // ---------------- phase B: log-softmax(t-1) || LSTM pointwise ----------------
    if (t > 0 && blk < 32){
      const int b = blk;
      const float* l0 = p.lp0 + (size_t)b*5008;
      const float* l1 = p.lp1 + (size_t)b*5008;
      float x[20];
      float m = -3.0e38f;
      #pragma unroll
      for (int i = 0; i < 20; i++){
        int v = tid + i*256;
        x[i] = (v < 5000) ? (l0[v] + l1[v] + rdf(p.blog, v, f)) : -3.0e38f;
        m = fmaxf(m, x[i]);
      }
      sRED[tid] = m; __syncthreads();
      for (int off = 128; off; off >>= 1){ if (tid < off) sRED[tid] = fmaxf(sRED[tid], sRED[tid+off]); __syncthreads(); }
      float M = sRED[0]; __syncthreads();
      float s = 0.f;
      #pragma unroll
      for (int i = 0; i < 20; i++){ int v = tid + i*256; if (v < 5000) s += __expf(x[i] - M); }
      sRED[tid] = s; __syncthreads();
      for (int off = 128; off; off >>= 1){ if (tid < off) sRED[tid] += sRED[tid+off]; __syncthreads(); }
      float lse = M + __logf(sRED[0]);
      const size_t ob = ((size_t)b*160 + (t-1))*5000;
      if (f){
        float* op = (float*)p.out;
        #pragma unroll
        for (int i = 0; i < 20; i++){ int v = tid + i*256; if (v < 5000) op[ob + v] = x[i] - lse; }
      } else {
        u16* op = (u16*)p.out;
        #pragma unroll
        for (int i = 0; i < 20; i++){ int v = tid + i*256; if (v < 5000) op[ob + v] = f2b(x[i] - lse); }
      }
    } else if (t < TT && blk >= 32 && blk < 64){
      const int b = blk - 32;
      const float* cold = p.cbuf + (size_t)(t & 1)*16384 + (size_t)b*512;
      float*       cnew = p.cbuf + (size_t)((t + 1) & 1)*16384 + (size_t)b*512;
      const float* g0 = p.gp0 + (size_t)b*2560;
      const float* g1 = p.gp1 + (size_t)b*2560;
      #pragma unroll
      for (int i = 0; i < 2; i++){
        const int j = tid + i*256;
        float gi = g0[j]      + g1[j]      + p.bg[j];
        float gf = g0[512+j]  + g1[512+j]  + p.bg[512+j];
        float gg = g0[1024+j] + g1[1024+j] + p.bg[1024+j];
        float go = g0[1536+j] + g1[1536+j] + p.bg[1536+j];
        float g5 = g0[2048+j] + g1[2048+j] + p.bg[2048+j];
        float cn = sigm(gf)*cold[j] + sigm(gi)*tanhp(gg);
        float tc = tanhp(cn);
        float hn = sigm(go)*tc;
        p.ab1[(size_t)b*1024 + j]       = f2b(sigm(g5)*tc);   // fr_pre
        p.ab1[(size_t)b*1024 + 512 + j] = f2b(hn);            // h_n
        cnew[j] = cn;
        p.zb[(size_t)b*1280 + 768 + j] = f2b(hn);
      }
      if (t < TT - 1)
        p.zb[(size_t)b*1280 + tid] = p.xe[((size_t)(t + 1)*32 + b)*256 + tid];
    }
    if (t == TT) break;
    gbar(p.bar, gen);

    // ---------------- phase C: AB2 = act(AB1 @ diag(Wfr,Who) + bias) ----------------
    if (blk < 16){
      const int job = blk*4 + wv;              // 0..63
      const int n0 = job*16;
      const u16* Bp = p.w45 + (size_t)(n0 + lr)*1024 + lq*8;
      const u16* Ap = p.ab1 + (size_t)lr*1024 + lq*8;
      f4 a0 = {0,0,0,0}, a1 = {0,0,0,0};
      #pragma unroll 8
      for (int ks = 0; ks < 32; ++ks){
        s8 fa0 = *(const s8*)(Ap + ks*32);
        s8 fa1 = *(const s8*)(Ap + 16*1024 + ks*32);
        s8 fb  = *(const s8*)(Bp + ks*32);
        a0 = __builtin_amdgcn_mfma_f32_16x16x32_bf16(fa0, fb, a0, 0, 0, 0);
        a1 = __builtin_amdgcn_mfma_f32_16x16x32_bf16(fa1, fb, a1, 0, 0, 0);
      }
      const int col = n0 + lr, r0 = lq*4;
      #pragma unroll
      for (int r = 0; r < 4; ++r){
        float v0 = a0[r], v1 = a1[r];
        if (col < 512){ float bb = rdf(p.bfr, col, f); v0 = fmaxf(v0 + bb, 0.f); v1 = fmaxf(v1 + bb, 0.f); }
        else          { float bb = rdf(p.bho, col - 512, f); v0 = tanhp(v0 + bb); v1 = tanhp(v1 + bb); }
        p.ab2[(size_t)(r0 + r)*1024 + col]      = f2b(v0);
        p.ab2[(size_t)(16 + r0 + r)*1024 + col] = f2b(v1);
      }
    }
    gbar(p.bar, gen);

    // ---------------- phase D: V4 = AB2 @ [Wfre|Whoe|Watt|Watt] ----------------
    if (blk < 32){
      const int job = blk*4 + wv;              // 0..127
      const int n0 = job*16;
      const u16* Bp = p.w6 + (size_t)(n0 + lr)*1024 + lq*8;
      const u16* Ap = p.ab2 + (size_t)lr*1024 + lq*8;
      f4 a0 = {0,0,0,0}, a1 = {0,0,0,0};
      #pragma unroll 8
      for (int ks = 0; ks < 32; ++ks){
        s8 fa0 = *(const s8*)(Ap + ks*32);
        s8 fa1 = *(const s8*)(Ap + 16*1024 + ks*32);
        s8 fb  = *(const s8*)(Bp + ks*32);
        a0 = __builtin_amdgcn_mfma_f32_16x16x32_bf16(fa0, fb, a0, 0, 0, 0);
        a1 = __builtin_amdgcn_mfma_f32_16x16x32_bf16(fa1, fb, a1, 0, 0, 0);
      }
      const int col = n0 + lr, r0 = lq*4;
      float add = 0.f;
      if (col < 512)        add = rdf(p.bfre, col, f);
      else if (col < 1024)  add = rdf(p.bhoe, col - 512, f);
      #pragma unroll
      for (int r = 0; r < 4; ++r){
        p.v4[(size_t)(r0 + r)*2048 + col]      = a0[r] + add;
        p.v4[(size_t)(16 + r0 + r)*2048 + col] = a1[r] + add;
      }
    }
    gbar(p.bar, gen);

    // ---------------- phase EF: scores + softmax + vis + out_h -> zb ----------------
    if (blk < 32){
      const int b = blk;
      const float* v4 = p.v4 + (size_t)b*2048;
      for (int i = tid; i < 512; i += 256){
        sFRE[i] = v4[i]; sHOE[i] = v4[512 + i]; sWa[i] = rdf(p.Wa, i, f);
      }
      __syncthreads();
      // scores over 257 atoms, lane covers 8 h's
      const int h0 = lane*8;
      for (int a = wv; a < 257; a += 4){
        float pp = 0.f;
        if (a == 0){
          #pragma unroll
          for (int j = 0; j < 8; ++j){ int h = h0 + j; pp += tanhp(sFRE[h] + sHOE[h]) * sWa[h]; }
        } else {
          s8 c8 = *(const s8*)(p.CE + ((size_t)b*256 + (a - 1))*512 + h0);
          #pragma unroll
          for (int j = 0; j < 8; ++j){ int h = h0 + j; pp += tanhp(b2f((u16)c8[j]) + sHOE[h]) * sWa[h]; }
        }
        #pragma unroll
        for (int o = 32; o; o >>= 1) pp += __shfl_xor(pp, o, 64);
        if (lane == 0) sP[a] = pp;
      }
      __syncthreads();
      // softmax over 257
      {
        float v0 = sP[tid];
        float v1 = (tid == 0) ? sP[256] : -3.0e38f;
        sRED[tid] = fmaxf(v0, v1); __syncthreads();
        for (int o = 128; o; o >>= 1){ if (tid < o) sRED[tid] = fmaxf(sRED[tid], sRED[tid+o]); __syncthreads(); }
        float M = sRED[0]; __syncthreads();
        float e0 = __expf(v0 - M), e1 = (tid == 0) ? __expf(v1 - M) : 0.f;
        sRED[tid] = e0 + e1; __syncthreads();
        for (int o = 128; o; o >>= 1){ if (tid < o) sRED[tid] += sRED[tid+o]; __syncthreads(); }
        float rS = 1.0f / sRED[0]; __syncthreads();
        sP[tid] = e0 * rS;
        if (tid == 0) sP[256] = e1 * rS;
      }
      __syncthreads();
      // vis partials: wave covers full 512 cols (lane*8), a-split across waves
      {
        float acc[8] = {0,0,0,0,0,0,0,0};
        for (int a = wv; a < 257; a += 4){
          float wgt = sP[a];
          if (a == 0){
            const float* frw = v4 + 1024 + h0;
            #pragma unroll
            for (int j = 0; j < 8; ++j) acc[j] += wgt * frw[j];
          } else {
            s8 c8 = *(const s8*)(p.CW + ((size_t)b*256 + (a - 1))*512 + h0);
            #pragma unroll
            for (int j = 0; j < 8; ++j) acc[j] += wgt * b2f((u16)c8[j]);
          }
        }
        #pragma unroll
        for (int j = 0; j < 8; ++j) sV[wv][h0 + j] = acc[j];
      }
      __syncthreads();
      #pragma unroll
      for (int i = 0; i < 2; ++i){
        int col = tid + i*256;
        float s = sV[0][col] + sV[1][col] + sV[2][col] + sV[3][col]
                + v4[1536 + col] + rdf(p.batt, col, f);
        p.zb[(size_t)b*1280 + 256 + col] = f2b(tanhp(s));
      }
    }
    gbar(p.bar, gen);
  }
}

// ---------------- host launch ----------------
extern "C" void kernel_launch(void* const* d_in, const int* in_sizes, int n_in,
                              void* d_out, int out_size, void* d_ws, size_t ws_size,
                              hipStream_t stream){
  char* w = (char*)d_ws;
  u16*   ZB  = (u16*)(w + oZB);
  float* CB  = (float*)(w + oC);
  int*   FLAG= (int*)(w + oFLAG);
  u16*   WT1 = (u16*)(w + oWT1);
  u16*   WT2 = (u16*)(w + oWT2);
  u16*   WT3 = (u16*)(w + oWT3);
  float* BG  = (float*)(w + oBG);
  u16*   XE  = (u16*)(w + oXE);
  u16*   CE  = (u16*)(w + oCE);
  u16*   CW  = (u16*)(w + oCW);
  u16*   W45T= (u16*)(w + oW45T);
  u16*   W6T = (u16*)(w + oW6T);

  (void)hipMemsetAsync(w, 0, ZERO_END, stream);                  // zb, c, flag, barrier
  (void)hipMemsetAsync(w + oWT2, 0, (size_t)5008*512*2, stream); // WT2 incl. pad
  (void)hipMemsetAsync(w + oW45T, 0, (size_t)(2097152 + 4194304), stream); // W45T+W6T

  const int* seq  = (const int*)d_in[1];

  probek<<<1, 256, 0, stream>>>((const u16*)d_in[0], FLAG);

  auto T = [&](const void* src, u16* dst, int R, int C, int stride){
    tposek<<<dim3((C + 31)/32, (R + 31)/32), 256, 0, stream>>>(src, dst, R, C, stride, FLAG);
  };
  T(d_in[5],  WT1,                              768, 2048, 1280);  // Wih
  T(d_in[7],  WT1 + 768,                        512, 2048, 1280);  // Whh
  T(d_in[9],  WT1 + (size_t)2048*1280,          768,  512, 1280);  // Wi2h
  T(d_in[11], WT1 + (size_t)2048*1280 + 768,    512,  512, 1280);  // Wh2h
  T(d_in[25], WT2,                              512, 5000,  512);  // Wlog
  T(d_in[3],  WT3,                              512,  512,  512);  // Wce
  T(d_in[23], WT3 + (size_t)512*512,            512,  512,  512);  // Watt (ctx)
  T(d_in[13], W45T,                             512,  512, 1024);  // Wfr
  T(d_in[17], W45T + (size_t)512*1024 + 512,    512,  512, 1024);  // Who
  T(d_in[15], W6T,                              512,  512, 1024);  // Wfre
  T(d_in[19], W6T + (size_t)512*1024 + 512,     512,  512, 1024);  // Whoe
  T(d_in[23], W6T + (size_t)1024*1024,          512,  512, 1024);  // Watt (frW)
  T(d_in[23], W6T + (size_t)1536*1024 + 512,    512,  512, 1024);  // Watt (holW)

  biask<<<10, 256, 0, stream>>>(d_in[6], d_in[8], d_in[10], d_in[12], BG, FLAG);
  xembk<<<dim3(160, 32), 256, 0, stream>>>(seq, d_in[2], XE, ZB, FLAG);
  ctxgemm<<<512, 256, 0, stream>>>(d_in[0], WT3, d_in[4], CE, CW, FLAG);

  DP p;
  p.bfr  = d_in[14]; p.bfre = d_in[16];
  p.bho  = d_in[18]; p.bhoe = d_in[20];
  p.Wa   = d_in[21]; p.batt = d_in[24];
  p.blog = d_in[26];
  p.WT1 = WT1; p.WT2 = WT2; p.xe = XE; p.CE = CE; p.CW = CW;
  p.w45 = W45T; p.w6 = W6T;
  p.bg = BG; p.flag = FLAG; p.zb = ZB; p.cbuf = CB;
  p.ab1 = (u16*)(w + oAB1); p.ab2 = (u16*)(w + oAB2);
  p.v4  = (float*)(w + oV4);
  p.gp0 = (float*)(w + oGP0); p.gp1 = (float*)(w + oGP1);
  p.lp0 = (float*)(w + oLP0); p.lp1 = (float*)(w + oLP1);
  p.bar = (unsigned*)(w + oBAR);
  p.out = d_out;

  loopk<<<NBLK, 256, 0, stream>>>(p);
}

// Round 3
// 24287.373 us; speedup vs baseline: 1.3303x; 1.3303x over previous
//
#include <hip/hip_runtime.h>

// AdaDecoder — persistent kernel, fence-free grid barrier (round 9).
// R8 post-mortem: 805 barriers x ~40us; __threadfence() = full L2 wb/inv per
// phase -> weights refetched every step (FETCH 15MB/step), 98% idle.
// Fix: NO fences anywhere in the loop. Cross-phase activations (zb, gp, lp,
// ab1, ab2, v4) are accessed ONLY via relaxed agent-scope atomics (sc1 ->
// bypass L2, read/write device coherence point). Weights use normal cached
// loads and stay L2-resident for all 161 steps. Barrier: __syncthreads()
// (drains vmcnt -> bypass stores visible) + relaxed fetch_add + relaxed poll.
// u16 outputs staged in LDS, packed to 8B atomic stores.

typedef unsigned short u16;
typedef unsigned long long u64;
typedef __attribute__((ext_vector_type(8))) short s8;
typedef __attribute__((ext_vector_type(4))) float f4;

#define TT 160
#define NBLK 240

// ---------------- ws layout (bytes) ----------------
static constexpr size_t oZB   = 0;              // u16 zb[32][1280]  (xt|out_prev|h)
static constexpr size_t oC    = 81920;          // float c[2][32][512]
static constexpr size_t oFLAG = 212992;         // int dtype flag (1 = fp32 inputs)
static constexpr size_t oBAR  = 213504;         // unsigned barrier counter (own line)
static constexpr size_t ZERO_END = 217088;
static constexpr size_t oWT1  = 217088;         // u16 [2560][1280]  gates/n5 W^T
static constexpr size_t oWT2  = 6770688;        // u16 [5008][512]   Wlog^T (padded)
static constexpr size_t oWT3  = 11898880;       // u16 [1024][512]   [Wce^T | Watt^T]
static constexpr size_t oBG   = 12947456;       // float bg[2560]
static constexpr size_t oXE   = 12957696;       // u16 xemb[160][32][256]
static constexpr size_t oCE   = 15579136;       // u16 CE[32][256][512]
static constexpr size_t oCW   = 23967744;       // u16 CW[32][256][512]
static constexpr size_t oGP0  = 32356352;       // float gp0[32][2560]
static constexpr size_t oGP1  = 32684032;
static constexpr size_t oLP0  = 33011712;       // float lp0[32][5008]
static constexpr size_t oLP1  = 33652736;       // end 34293760
static constexpr size_t oAB1  = 34293760;       // u16 [32][1024]  [fr_pre|h]
static constexpr size_t oAB2  = 34359296;       // u16 [32][1024]  [fr|hol]
static constexpr size_t oV4   = 34424832;       // float [32][2048] [fre|hoe|frW|holW]
static constexpr size_t oW45T = 34686976;       // u16 [1024][1024] diag(Wfr^T,Who^T)
static constexpr size_t oW6T  = 36784128;       // u16 [2048][1024] big B^T
                                                // end 40978432

__device__ __forceinline__ float b2f(u16 u){ return __uint_as_float(((unsigned)u) << 16); }
__device__ __forceinline__ u16 f2b(float f){
  unsigned x = __float_as_uint(f);
  return (u16)((x + 0x7fffu + ((x >> 16) & 1u)) >> 16);
}
__device__ __forceinline__ float sigm(float x){ return 1.0f/(1.0f + __expf(-x)); }
__device__ __forceinline__ float tanhp(float x){ return 1.0f - 2.0f/(__expf(2.0f*x) + 1.0f); }
__device__ __forceinline__ u16 rdb(const void* p, size_t i, int f){
  return f ? f2b(((const float*)p)[i]) : ((const u16*)p)[i];
}
__device__ __forceinline__ float rdf(const void* p, size_t i, int f){
  return f ? ((const float*)p)[i] : b2f(((const u16*)p)[i]);
}

// ---- coherent (L2-bypass) accessors: relaxed agent-scope atomics ----
__device__ __forceinline__ float ldf(const float* p){
  return __hip_atomic_load((float*)p, __ATOMIC_RELAXED, __HIP_MEMORY_SCOPE_AGENT);
}
__device__ __forceinline__ void stf(float* p, float v){
  __hip_atomic_store(p, v, __ATOMIC_RELAXED, __HIP_MEMORY_SCOPE_AGENT);
}
__device__ __forceinline__ u64 ld64(const void* p){
  return __hip_atomic_load((u64*)p, __ATOMIC_RELAXED, __HIP_MEMORY_SCOPE_AGENT);
}
__device__ __forceinline__ void st64(void* p, u64 v){
  __hip_atomic_store((u64*)p, v, __ATOMIC_RELAXED, __HIP_MEMORY_SCOPE_AGENT);
}
__device__ __forceinline__ s8 ld128(const void* p){
  union { u64 q[2]; s8 v; } u;
  u.q[0] = ld64(p);
  u.q[1] = ld64((const char*)p + 8);
  return u.v;
}

// Fence-free grid barrier. __syncthreads() drains vmcnt (all bypass stores at
// coherence point); arrival/poll are relaxed agent atomics; NO buffer_wbl2/inv.
__device__ __forceinline__ void gbar(unsigned* cnt, unsigned& gen){
  __syncthreads();
  if (threadIdx.x == 0){
    gen += NBLK;
    __hip_atomic_fetch_add(cnt, 1u, __ATOMIC_RELAXED, __HIP_MEMORY_SCOPE_AGENT);
    while (__hip_atomic_load(cnt, __ATOMIC_RELAXED, __HIP_MEMORY_SCOPE_AGENT) < gen)
      __builtin_amdgcn_s_sleep(2);
  }
  __syncthreads();
}

// ---------------- probe: detect input dtype ----------------
__global__ void probek(const u16* __restrict__ a, int* flag){
  __shared__ int s[256];
  int t = threadIdx.x;
  float v = fabsf(b2f(a[t]));
  s[t] = (v < 64.0f) ? 0 : 1;
  __syncthreads();
  for (int o = 128; o; o >>= 1){ if (t < o) s[t] += s[t+o]; __syncthreads(); }
  if (t == 0) *flag = (s[0] > 0) ? 1 : 0;
}

// ---------------- preamble kernels ----------------
// dst[n*stride + k] = src[k*C + n]
__global__ void tposek(const void* __restrict__ src, u16* __restrict__ dst,
                       int R, int C, int stride, const int* __restrict__ flag){
  __shared__ u16 tl[32][33];
  const int f = *flag;
  int nt = blockIdx.x*32, kt = blockIdx.y*32;
  int tx = threadIdx.x & 31, ty = threadIdx.x >> 5;
  #pragma unroll
  for (int i = 0; i < 4; i++){
    int k = kt + ty + i*8, n = nt + tx;
    tl[ty + i*8][tx] = (k < R && n < C) ? rdb(src, (size_t)k*C + n, f) : (u16)0;
  }
  __syncthreads();
  #pragma unroll
  for (int i = 0; i < 4; i++){
    int n = nt + ty + i*8, k = kt + tx;
    if (n < C && k < R) dst[(size_t)n*stride + k] = tl[tx][ty + i*8];
  }
}

__global__ void biask(const void* bih, const void* bhh, const void* bi2h, const void* bh2h,
                      float* bg, const int* __restrict__ flag){
  const int f = *flag;
  int n = blockIdx.x*256 + threadIdx.x;
  if (n >= 2560) return;
  if (n < 2048) bg[n] = rdf(bih, n, f) + rdf(bhh, n, f);
  else { int j = n - 2048; bg[n] = rdf(bi2h, j, f) + rdf(bh2h, j, f); }
}

__global__ void xembk(const int* __restrict__ seq, const void* __restrict__ embed,
                      u16* __restrict__ xe, u16* __restrict__ zb,
                      const int* __restrict__ flag){
  const int f = *flag;
  int t = blockIdx.x, b = blockIdx.y, e = threadIdx.x;
  int idx = seq[b*161 + t];
  u16 v = rdb(embed, (size_t)idx*256 + e, f);
  xe[((size_t)t*32 + b)*256 + e] = v;
  if (t == 0) zb[(size_t)b*1280 + e] = v;
}

// CE = relu(cnn@Wce + bce), CW = cnn@Watt   (M=8192, N=1024, K=512)
__global__ __launch_bounds__(256) void ctxgemm(const void* __restrict__ A,
                                               const u16* __restrict__ WT3,
                                               const void* __restrict__ bce,
                                               u16* __restrict__ CE, u16* __restrict__ CW,
                                               const int* __restrict__ flag){
  const int f = *flag;
  int wave = threadIdx.x >> 6, lane = threadIdx.x & 63;
  int job = blockIdx.x*4 + wave;
  int mq = job >> 4, nq = job & 15;
  int m0 = mq*64, n0 = nq*64;
  int lr = lane & 15, lq = lane >> 4;
  f4 acc[4][4] = {};
  for (int ks = 0; ks < 16; ks++){
    int k0 = ks*32 + lq*8;
    s8 a[4], b[4];
    #pragma unroll
    for (int mt = 0; mt < 4; mt++){
      size_t base = (size_t)(m0 + mt*16 + lr)*512 + k0;
      if (f){
        const float4* ap = (const float4*)((const float*)A + base);
        float4 q0 = ap[0], q1 = ap[1];
        union { u16 u[8]; s8 v; } pk;
        pk.u[0]=f2b(q0.x); pk.u[1]=f2b(q0.y); pk.u[2]=f2b(q0.z); pk.u[3]=f2b(q0.w);
        pk.u[4]=f2b(q1.x); pk.u[5]=f2b(q1.y); pk.u[6]=f2b(q1.z); pk.u[7]=f2b(q1.w);
        a[mt] = pk.v;
      } else {
        a[mt] = *(const s8*)((const u16*)A + base);
      }
    }
    #pragma unroll
    for (int nt = 0; nt < 4; nt++) b[nt] = *(const s8*)(WT3 + (size_t)(n0 + nt*16 + lr)*512 + k0);
    #pragma unroll
    for (int mt = 0; mt < 4; mt++)
      #pragma unroll
      for (int nt = 0; nt < 4; nt++)
        acc[mt][nt] = __builtin_amdgcn_mfma_f32_16x16x32_bf16(a[mt], b[nt], acc[mt][nt], 0, 0, 0);
  }
  #pragma unroll
  for (int mt = 0; mt < 4; mt++)
    #pragma unroll
    for (int nt = 0; nt < 4; nt++)
      #pragma unroll
      for (int r = 0; r < 4; r++){
        int row = m0 + mt*16 + lq*4 + r;
        int col = n0 + nt*16 + lr;
        float d = acc[mt][nt][r];
        if (col < 512){ d += rdf(bce, col, f); d = d > 0.f ? d : 0.f; CE[(size_t)row*512 + col] = f2b(d); }
        else CW[(size_t)row*512 + (col - 512)] = f2b(d);
      }
}

// ---------------- persistent step kernel ----------------
struct DP {
  const void *bfr, *bfre, *bho, *bhoe, *Wa, *batt, *blog;
  const u16 *WT1, *WT2, *xe, *CE, *CW, *w45, *w6;
  const float *bg;
  const int *flag;
  u16 *zb, *ab1, *ab2; float *cbuf, *v4;
  float *gp0, *gp1, *lp0, *lp1;
  unsigned *bar;
  void *out;
};

// NBLK blocks x 256 threads, persistent. Whole t-loop inside.
__global__ __launch_bounds__(256) void loopk(DP p){
  const int blk = blockIdx.x;
  const int tid = threadIdx.x, lane = tid & 63, wv = tid >> 6;
  const int lr = lane & 15, lq = lane >> 4;
  const int f = *p.flag;
  unsigned gen = 0;

  __shared__ float sFRE[512], sHOE[512], sWa[512], sP[257], sRED[256], sV[4][512];
  __shared__ u16 sPK[2048];   // u16 pack-staging (B: 1024, C: 2048, EF: 512)

  for (int t = 0; t <= TT; ++t){
    // ---------------- phase A: gates GEMM (t) + logits GEMM (t-1) ----------------
    {
      const int gwave = blk*4 + wv;
      if (t < TT && gwave < 320){
        const int nt = gwave >> 1, kh = gwave & 1;
        const u16* Bp = p.WT1 + (size_t)(nt*16 + lr)*1280 + kh*640 + lq*8;
        const u16* Ap = p.zb + (size_t)lr*1280 + kh*640 + lq*8;
        f4 a0 = {0,0,0,0}, a1 = {0,0,0,0};
        #pragma unroll 4
        for (int ks = 0; ks < 20; ++ks){
          s8 fa0 = ld128(Ap + ks*32);
          s8 fa1 = ld128(Ap + 16*1280 + ks*32);
          s8 fb  = *(const s8*)(Bp + ks*32);
          a0 = __builtin_amdgcn_mfma_f32_16x16x32_bf16(fa0, fb, a0, 0, 0, 0);
          a1 = __builtin_amdgcn_mfma_f32_16x16x32_bf16(fa1, fb, a1, 0, 0, 0);
        }
        float* gp = kh ? p.gp1 : p.gp0;
        const int col = nt*16 + lr, r0 = lq*4;
        #pragma unroll
        for (int r = 0; r < 4; ++r){
          stf(gp + (size_t)(r0 + r)*2560 + col, a0[r]);
          stf(gp + (size_t)(16 + r0 + r)*2560 + col, a1[r]);
        }
      } else if (t > 0 && gwave >= 320 && gwave < 946){
        const int j = gwave - 320, nt = j >> 1, kh = j & 1;
        const u16* Bp = p.WT2 + (size_t)(nt*16 + lr)*512 + kh*256 + lq*8;
        const u16* Ap = p.zb + 256 + (size_t)lr*1280 + kh*256 + lq*8;
        f4 a0 = {0,0,0,0}, a1 = {0,0,0,0};
        #pragma unroll
        for (int ks = 0; ks < 8; ++ks){
          s8 fa0 = ld128(Ap + ks*32);
          s8 fa1 = ld128(Ap + 16*1280 + ks*32);
          s8 fb  = *(const s8*)(Bp + ks*32);
          a0 = __builtin_amdgcn_mfma_f32_16x16x32_bf16(fa0, fb, a0, 0, 0, 0);
          a1 = __builtin_amdgcn_mfma_f32_16x16x32_bf16(fa1, fb, a1, 0, 0, 0);
        }
        float* lp = kh ? p.lp1 : p.lp0;
        const int col = nt*16 + lr, r0 = lq*4;
        #pragma unroll
        for (int r = 0; r < 4; ++r){
          stf(lp + (size_t)(r0 + r)*5008 + col, a0[r]);
          stf(lp + (size_t)(16 + r0 + r)*5008 + col, a1[r]);
        }
      }
    }
    gbar(p.bar, gen);

    // ---------------- phase B: log-softmax(t-1) || LSTM pointwise ----------------
    if (t > 0 && blk < 32){
      const int b = blk;
      const float* l0 = p.lp0 + (size_t)b*5008;
      const float* l1 = p.lp1 + (size_t)b*5008;
      float x[20];
      float m = -3.0e38f;
      #pragma unroll
      for (int i = 0; i < 20; i++){
        int v = tid + i*256;
        x[i] = (v < 5000) ? (ldf(l0 + v) + ldf(l1 + v) + rdf(p.blog, v, f)) : -3.0e38f;
        m = fmaxf(m, x[i]);
      }
      sRED[tid] = m; __syncthreads();
      for (int off = 128; off; off >>= 1){ if (tid < off) sRED[tid] = fmaxf(sRED[tid], sRED[tid+off]); __syncthreads(); }
      float M = sRED[0]; __syncthreads();
      float s = 0.f;
      #pragma unroll
      for (int i = 0; i < 20; i++){ int v = tid + i*256; if (v < 5000) s += __expf(x[i] - M); }
      sRED[tid] = s; __syncthreads();
      for (int off = 128; off; off >>= 1){ if (tid < off) sRED[tid] += sRED[tid+off]; __syncthreads(); }
      float lse = M + __logf(sRED[0]);
      const size_t ob = ((size_t)b*160 + (t-1))*5000;
      if (f){
        float* op = (float*)p.out;
        #pragma unroll
        for (int i = 0; i < 20; i++){ int v = tid + i*256; if (v < 5000) op[ob + v] = x[i] - lse; }
      } else {
        u16* op = (u16*)p.out;
        #pragma unroll
        for (int i = 0; i < 20; i++){ int v = tid + i*256; if (v < 5000) op[ob + v] = f2b(x[i] - lse); }
      }
    } else if (t < TT && blk >= 32 && blk < 64){
      const int b = blk - 32;
      const float* cold = p.cbuf + (size_t)(t & 1)*16384 + (size_t)b*512;
      float*       cnew = p.cbuf + (size_t)((t + 1) & 1)*16384 + (size_t)b*512;
      const float* g0 = p.gp0 + (size_t)b*2560;
      const float* g1 = p.gp1 + (size_t)b*2560;
      #pragma unroll
      for (int i = 0; i < 2; i++){
        const int j = tid + i*256;
        float gi = ldf(g0 + j)        + ldf(g1 + j)        + p.bg[j];
        float gf = ldf(g0 + 512 + j)  + ldf(g1 + 512 + j)  + p.bg[512+j];
        float gg = ldf(g0 + 1024 + j) + ldf(g1 + 1024 + j) + p.bg[1024+j];
        float go = ldf(g0 + 1536 + j) + ldf(g1 + 1536 + j) + p.bg[1536+j];
        float g5 = ldf(g0 + 2048 + j) + ldf(g1 + 2048 + j) + p.bg[2048+j];
        float cn = sigm(gf)*cold[j] + sigm(gi)*tanhp(gg);
        float tc = tanhp(cn);
        float hn = sigm(go)*tc;
        sPK[j]       = f2b(sigm(g5)*tc);   // fr_pre
        sPK[512 + j] = f2b(hn);            // h_n
        cnew[j] = cn;
      }
      __syncthreads();
      // pack to 8B coherent stores: ab1 row b (1024 u16), zb.h (512 u16), xt (256 u16)
      st64(p.ab1 + (size_t)b*1024 + tid*4, *(const u64*)(sPK + tid*4));
      if (tid < 128)
        st64(p.zb + (size_t)b*1280 + 768 + tid*4, *(const u64*)(sPK + 512 + tid*4));
      if (t < TT - 1 && tid < 64){
        u64 q = *(const u64*)(p.xe + ((size_t)(t + 1)*32 + b)*256 + tid*4);
        st64(p.zb + (size_t)b*1280 + tid*4, q);
      }
    }
    if (t == TT) break;
    gbar(p.bar, gen);

    // ---------------- phase C: AB2 = act(AB1 @ diag(Wfr,Who) + bias) ----------------
    if (blk < 16){
      const int job = blk*4 + wv;              // 0..63
      const int n0 = job*16;
      const u16* Bp = p.w45 + (size_t)(n0 + lr)*1024 + lq*8;
      const u16* Ap = p.ab1 + (size_t)lr*1024 + lq*8;
      f4 a0 = {0,0,0,0}, a1 = {0,0,0,0};
      #pragma unroll 8
      for (int ks = 0; ks < 32; ++ks){
        s8 fa0 = ld128(Ap + ks*32);
        s8 fa1 = ld128(Ap + 16*1024 + ks*32);
        s8 fb  = *(const s8*)(Bp + ks*32);
        a0 = __builtin_amdgcn_mfma_f32_16x16x32_bf16(fa0, fb, a0, 0, 0, 0);
        a1 = __builtin_amdgcn_mfma_f32_16x16x32_bf16(fa1, fb, a1, 0, 0, 0);
      }
      const int col = n0 + lr, r0 = lq*4;
      const int lcol = wv*16 + lr;             // 0..63 within block's 64-col slab
      #pragma unroll
      for (int r = 0; r < 4; ++r){
        float v0 = a0[r], v1 = a1[r];
        if (col < 512){ float bb = rdf(p.bfr, col, f); v0 = fmaxf(v0 + bb, 0.f); v1 = fmaxf(v1 + bb, 0.f); }
        else          { float bb = rdf(p.bho, col - 512, f); v0 = tanhp(v0 + bb); v1 = tanhp(v1 + bb); }
        sPK[(r0 + r)*64 + lcol]      = f2b(v0);
        sPK[(16 + r0 + r)*64 + lcol] = f2b(v1);
      }
      __syncthreads();
      // repack: rows 0..31 x 64 cols -> 8B coherent stores
      const int row = tid >> 3, c0 = (tid & 7)*8;
      const u16* s = sPK + row*64 + c0;
      u16* dstp = p.ab2 + (size_t)row*1024 + blk*64 + c0;
      st64(dstp,     *(const u64*)s);
      st64(dstp + 4, *(const u64*)(s + 4));
    }
    gbar(p.bar, gen);

    // ---------------- phase D: V4 = AB2 @ [Wfre|Whoe|Watt|Watt] ----------------
    if (blk < 32){
      const int job = blk*4 + wv;              // 0..127
      const int n0 = job*16;
      const u16* Bp = p.w6 + (size_t)(n0 + lr)*1024 + lq*8;
      const u16* Ap = p.ab2 + (size_t)lr*1024 + lq*8;
      f4 a0 = {0,0,0,0}, a1 = {0,0,0,0};
      #pragma unroll 8
      for (int ks = 0; ks < 32; ++ks){
        s8 fa0 = ld128(Ap + ks*32);
        s8 fa1 = ld128(Ap + 16*1024 + ks*32);
        s8 fb  = *(const s8*)(Bp + ks*32);
        a0 = __builtin_amdgcn_mfma_f32_16x16x32_bf16(fa0, fb, a0, 0, 0, 0);
        a1 = __builtin_amdgcn_mfma_f32_16x16x32_bf16(fa1, fb, a1, 0, 0, 0);
      }
      const int col = n0 + lr, r0 = lq*4;
      float add = 0.f;
      if (col < 512)        add = rdf(p.bfre, col, f);
      else if (col < 1024)  add = rdf(p.bhoe, col - 512, f);
      #pragma unroll
      for (int r = 0; r < 4; ++r){
        stf(p.v4 + (size_t)(r0 + r)*2048 + col,      a0[r] + add);
        stf(p.v4 + (size_t)(16 + r0 + r)*2048 + col, a1[r] + add);
      }
    }
    gbar(p.bar, gen);

    // ---------------- phase EF: scores + softmax + vis + out_h -> zb ----------------
    if (blk < 32){
      const int b = blk;
      const float* v4 = p.v4 + (size_t)b*2048;
      for (int i = tid; i < 512; i += 256){
        sFRE[i] = ldf(v4 + i); sHOE[i] = ldf(v4 + 512 + i); sWa[i] = rdf(p.Wa, i, f);
      }
      __syncthreads();
      // scores over 257 atoms, lane covers 8 h's
      const int h0 = lane*8;
      for (int a = wv; a < 257; a += 4){
        float pp = 0.f;
        if (a == 0){
          #pragma unroll
          for (int j = 0; j < 8; ++j){ int h = h0 + j; pp += tanhp(sFRE[h] + sHOE[h]) * sWa[h]; }
        } else {
          s8 c8 = *(const s8*)(p.CE + ((size_t)b*256 + (a - 1))*512 + h0);
          #pragma unroll
          for (int j = 0; j < 8; ++j){ int h = h0 + j; pp += tanhp(b2f((u16)c8[j]) + sHOE[h]) * sWa[h]; }
        }
        #pragma unroll
        for (int o = 32; o; o >>= 1) pp += __shfl_xor(pp, o, 64);
        if (lane == 0) sP[a] = pp;
      }
      __syncthreads();
      // softmax over 257
      {
        float v0 = sP[tid];
        float v1 = (tid == 0) ? sP[256] : -3.0e38f;
        sRED[tid] = fmaxf(v0, v1); __syncthreads();
        for (int o = 128; o; o >>= 1){ if (tid < o) sRED[tid] = fmaxf(sRED[tid], sRED[tid+o]); __syncthreads(); }
        float M = sRED[0]; __syncthreads();
        float e0 = __expf(v0 - M), e1 = (tid == 0) ? __expf(v1 - M) : 0.f;
        sRED[tid] = e0 + e1; __syncthreads();
        for (int o = 128; o; o >>= 1){ if (tid < o) sRED[tid] += sRED[tid+o]; __syncthreads(); }
        float rS = 1.0f / sRED[0]; __syncthreads();
        sP[tid] = e0 * rS;
        if (tid == 0) sP[256] = e1 * rS;
      }
      __syncthreads();
      // vis partials: wave covers full 512 cols (lane*8), a-split across waves
      {
        float acc[8] = {0,0,0,0,0,0,0,0};
        for (int a = wv; a < 257; a += 4){
          float wgt = sP[a];
          if (a == 0){
            #pragma unroll
            for (int j = 0; j < 8; ++j) acc[j] += wgt * ldf(v4 + 1024 + h0 + j);
          } else {
            s8 c8 = *(const s8*)(p.CW + ((size_t)b*256 + (a - 1))*512 + h0);
            #pragma unroll
            for (int j = 0; j < 8; ++j) acc[j] += wgt * b2f((u16)c8[j]);
          }
        }
        #pragma unroll
        for (int j = 0; j < 8; ++j) sV[wv][h0 + j] = acc[j];
      }
      __syncthreads();
      #pragma unroll
      for (int i = 0; i < 2; ++i){
        int col = tid + i*256;
        float s = sV[0][col] + sV[1][col] + sV[2][col] + sV[3][col]
                + ldf(v4 + 1536 + col) + rdf(p.batt, col, f);
        sPK[col] = f2b(tanhp(s));
      }
      __syncthreads();
      if (tid < 128)
        st64(p.zb + (size_t)b*1280 + 256 + tid*4, *(const u64*)(sPK + tid*4));
    }
    gbar(p.bar, gen);
  }
}

// ---------------- host launch ----------------
extern "C" void kernel_launch(void* const* d_in, const int* in_sizes, int n_in,
                              void* d_out, int out_size, void* d_ws, size_t ws_size,
                              hipStream_t stream){
  char* w = (char*)d_ws;
  u16*   ZB  = (u16*)(w + oZB);
  float* CB  = (float*)(w + oC);
  int*   FLAG= (int*)(w + oFLAG);
  u16*   WT1 = (u16*)(w + oWT1);
  u16*   WT2 = (u16*)(w + oWT2);
  u16*   WT3 = (u16*)(w + oWT3);
  float* BG  = (float*)(w + oBG);
  u16*   XE  = (u16*)(w + oXE);
  u16*   CE  = (u16*)(w + oCE);
  u16*   CW  = (u16*)(w + oCW);
  u16*   W45T= (u16*)(w + oW45T);
  u16*   W6T = (u16*)(w + oW6T);

  (void)hipMemsetAsync(w, 0, ZERO_END, stream);                  // zb, c, flag, barrier
  (void)hipMemsetAsync(w + oWT2, 0, (size_t)5008*512*2, stream); // WT2 incl. pad
  (void)hipMemsetAsync(w + oW45T, 0, (size_t)(2097152 + 4194304), stream); // W45T+W6T

  const int* seq  = (const int*)d_in[1];

  probek<<<1, 256, 0, stream>>>((const u16*)d_in[0], FLAG);

  auto T = [&](const void* src, u16* dst, int R, int C, int stride){
    tposek<<<dim3((C + 31)/32, (R + 31)/32), 256, 0, stream>>>(src, dst, R, C, stride, FLAG);
  };
  T(d_in[5],  WT1,                              768, 2048, 1280);  // Wih
  T(d_in[7],  WT1 + 768,                        512, 2048, 1280);  // Whh
  T(d_in[9],  WT1 + (size_t)2048*1280,          768,  512, 1280);  // Wi2h
  T(d_in[11], WT1 + (size_t)2048*1280 + 768,    512,  512, 1280);  // Wh2h
  T(d_in[25], WT2,                              512, 5000,  512);  // Wlog
  T(d_in[3],  WT3,                              512,  512,  512);  // Wce
  T(d_in[23], WT3 + (size_t)512*512,            512,  512,  512);  // Watt (ctx)
  T(d_in[13], W45T,                             512,  512, 1024);  // Wfr
  T(d_in[17], W45T + (size_t)512*1024 + 512,    512,  512, 1024);  // Who
  T(d_in[15], W6T,                              512,  512, 1024);  // Wfre
  T(d_in[19], W6T + (size_t)512*1024 + 512,     512,  512, 1024);  // Whoe
  T(d_in[23], W6T + (size_t)1024*1024,          512,  512, 1024);  // Watt (frW)
  T(d_in[23], W6T + (size_t)1536*1024 + 512,    512,  512, 1024);  // Watt (holW)

  biask<<<10, 256, 0, stream>>>(d_in[6], d_in[8], d_in[10], d_in[12], BG, FLAG);
  xembk<<<dim3(160, 32), 256, 0, stream>>>(seq, d_in[2], XE, ZB, FLAG);
  ctxgemm<<<512, 256, 0, stream>>>(d_in[0], WT3, d_in[4], CE, CW, FLAG);

  DP p;
  p.bfr  = d_in[14]; p.bfre = d_in[16];
  p.bho  = d_in[18]; p.bhoe = d_in[20];
  p.Wa   = d_in[21]; p.batt = d_in[24];
  p.blog = d_in[26];
  p.WT1 = WT1; p.WT2 = WT2; p.xe = XE; p.CE = CE; p.CW = CW;
  p.w45 = W45T; p.w6 = W6T;
  p.bg = BG; p.flag = FLAG; p.zb = ZB; p.cbuf = CB;
  p.ab1 = (u16*)(w + oAB1); p.ab2 = (u16*)(w + oAB2);
  p.v4  = (float*)(w + oV4);
  p.gp0 = (float*)(w + oGP0); p.gp1 = (float*)(w + oGP1);
  p.lp0 = (float*)(w + oLP0); p.lp1 = (float*)(w + oLP1);
  p.bar = (unsigned*)(w + oBAR);
  p.out = d_out;

  loopk<<<NBLK, 256, 0, stream>>>(p);
}

// Round 4
// 23146.950 us; speedup vs baseline: 1.3958x; 1.0493x over previous
//
#include <hip/hip_runtime.h>

// AdaDecoder — persistent kernel, distributed grid barrier (round 10).
// R9 post-mortem: fence removal didn't help -> the 240-block atomicAdd on ONE
// cacheline was the cost (~27us = 240 serialized RMWs at the coherence point).
// Fix: arrive/release barrier with NO RMW:
//   - each block STOREs its generation to its own 8B slot (no ownership xfer)
//   - block 0: threads 1..239 poll all slots in parallel (1 wave-round trip),
//     then thread 0 publishes a release word
//   - other blocks poll only the release word (read-only, broadcast)
// Activations still go through relaxed agent-scope (sc1, L2-bypass) atomics;
// weights stay normal cached loads (L2-resident across all 161 steps).

typedef unsigned short u16;
typedef unsigned long long u64;
typedef __attribute__((ext_vector_type(8))) short s8;
typedef __attribute__((ext_vector_type(4))) float f4;

#define TT 160
#define NBLK 240

// ---------------- ws layout (bytes) ----------------
static constexpr size_t oZB   = 0;              // u16 zb[32][1280]  (xt|out_prev|h)
static constexpr size_t oC    = 81920;          // float c[2][32][512]
static constexpr size_t oFLAG = 212992;         // int dtype flag (1 = fp32 inputs)
static constexpr size_t oSLOT = 213504;         // unsigned slots[240*2] (8B stride)
static constexpr size_t oREL  = 215488;         // unsigned release word (own line)
static constexpr size_t ZERO_END = 217088;
static constexpr size_t oWT1  = 217088;         // u16 [2560][1280]  gates/n5 W^T
static constexpr size_t oWT2  = 6770688;        // u16 [5008][512]   Wlog^T (padded)
static constexpr size_t oWT3  = 11898880;       // u16 [1024][512]   [Wce^T | Watt^T]
static constexpr size_t oBG   = 12947456;       // float bg[2560]
static constexpr size_t oXE   = 12957696;       // u16 xemb[160][32][256]
static constexpr size_t oCE   = 15579136;       // u16 CE[32][256][512]
static constexpr size_t oCW   = 23967744;       // u16 CW[32][256][512]
static constexpr size_t oGP0  = 32356352;       // float gp0[32][2560]
static constexpr size_t oGP1  = 32684032;
static constexpr size_t oLP0  = 33011712;       // float lp0[32][5008]
static constexpr size_t oLP1  = 33652736;       // end 34293760
static constexpr size_t oAB1  = 34293760;       // u16 [32][1024]  [fr_pre|h]
static constexpr size_t oAB2  = 34359296;       // u16 [32][1024]  [fr|hol]
static constexpr size_t oV4   = 34424832;       // float [32][2048] [fre|hoe|frW|holW]
static constexpr size_t oW45T = 34686976;       // u16 [1024][1024] diag(Wfr^T,Who^T)
static constexpr size_t oW6T  = 36784128;       // u16 [2048][1024] big B^T
                                                // end 40978432

__device__ __forceinline__ float b2f(u16 u){ return __uint_as_float(((unsigned)u) << 16); }
__device__ __forceinline__ u16 f2b(float f){
  unsigned x = __float_as_uint(f);
  return (u16)((x + 0x7fffu + ((x >> 16) & 1u)) >> 16);
}
__device__ __forceinline__ float sigm(float x){ return 1.0f/(1.0f + __expf(-x)); }
__device__ __forceinline__ float tanhp(float x){ return 1.0f - 2.0f/(__expf(2.0f*x) + 1.0f); }
__device__ __forceinline__ u16 rdb(const void* p, size_t i, int f){
  return f ? f2b(((const float*)p)[i]) : ((const u16*)p)[i];
}
__device__ __forceinline__ float rdf(const void* p, size_t i, int f){
  return f ? ((const float*)p)[i] : b2f(((const u16*)p)[i]);
}

// ---- coherent (L2-bypass) accessors: relaxed agent-scope atomics ----
__device__ __forceinline__ float ldf(const float* p){
  return __hip_atomic_load((float*)p, __ATOMIC_RELAXED, __HIP_MEMORY_SCOPE_AGENT);
}
__device__ __forceinline__ void stf(float* p, float v){
  __hip_atomic_store(p, v, __ATOMIC_RELAXED, __HIP_MEMORY_SCOPE_AGENT);
}
__device__ __forceinline__ u64 ld64(const void* p){
  return __hip_atomic_load((u64*)p, __ATOMIC_RELAXED, __HIP_MEMORY_SCOPE_AGENT);
}
__device__ __forceinline__ void st64(void* p, u64 v){
  __hip_atomic_store((u64*)p, v, __ATOMIC_RELAXED, __HIP_MEMORY_SCOPE_AGENT);
}
__device__ __forceinline__ s8 ld128(const void* p){
  union { u64 q[2]; s8 v; } u;
  u.q[0] = ld64(p);
  u.q[1] = ld64((const char*)p + 8);
  return u.v;
}

// Distributed arrive/release grid barrier (no RMW, no fences).
// Ordering: __syncthreads() -> compiler drains vmcnt (all sc1 stores at the
// coherence point) -> explicit vmcnt(0) belt-and-suspenders -> arrival store.
__device__ __forceinline__ void gbar(unsigned* slots, unsigned* rel, unsigned& gen){
  ++gen;                                   // uniform across all threads
  __syncthreads();
  asm volatile("s_waitcnt vmcnt(0)" ::: "memory");
  if (blockIdx.x == 0){
    const int tid = threadIdx.x;
    if (tid > 0 && tid < NBLK){
      while (__hip_atomic_load(slots + tid*2, __ATOMIC_RELAXED, __HIP_MEMORY_SCOPE_AGENT) < gen)
        __builtin_amdgcn_s_sleep(1);
    }
    __syncthreads();
    if (tid == 0)
      __hip_atomic_store(rel, gen, __ATOMIC_RELAXED, __HIP_MEMORY_SCOPE_AGENT);
  } else {
    if (threadIdx.x == 0){
      __hip_atomic_store(slots + blockIdx.x*2, gen, __ATOMIC_RELAXED, __HIP_MEMORY_SCOPE_AGENT);
      while (__hip_atomic_load(rel, __ATOMIC_RELAXED, __HIP_MEMORY_SCOPE_AGENT) < gen)
        __builtin_amdgcn_s_sleep(1);
    }
    __syncthreads();
  }
}

// ---------------- probe: detect input dtype ----------------
__global__ void probek(const u16* __restrict__ a, int* flag){
  __shared__ int s[256];
  int t = threadIdx.x;
  float v = fabsf(b2f(a[t]));
  s[t] = (v < 64.0f) ? 0 : 1;
  __syncthreads();
  for (int o = 128; o; o >>= 1){ if (t < o) s[t] += s[t+o]; __syncthreads(); }
  if (t == 0) *flag = (s[0] > 0) ? 1 : 0;
}

// ---------------- preamble kernels ----------------
// dst[n*stride + k] = src[k*C + n]
__global__ void tposek(const void* __restrict__ src, u16* __restrict__ dst,
                       int R, int C, int stride, const int* __restrict__ flag){
  __shared__ u16 tl[32][33];
  const int f = *flag;
  int nt = blockIdx.x*32, kt = blockIdx.y*32;
  int tx = threadIdx.x & 31, ty = threadIdx.x >> 5;
  #pragma unroll
  for (int i = 0; i < 4; i++){
    int k = kt + ty + i*8, n = nt + tx;
    tl[ty + i*8][tx] = (k < R && n < C) ? rdb(src, (size_t)k*C + n, f) : (u16)0;
  }
  __syncthreads();
  #pragma unroll
  for (int i = 0; i < 4; i++){
    int n = nt + ty + i*8, k = kt + tx;
    if (n < C && k < R) dst[(size_t)n*stride + k] = tl[tx][ty + i*8];
  }
}

__global__ void biask(const void* bih, const void* bhh, const void* bi2h, const void* bh2h,
                      float* bg, const int* __restrict__ flag){
  const int f = *flag;
  int n = blockIdx.x*256 + threadIdx.x;
  if (n >= 2560) return;
  if (n < 2048) bg[n] = rdf(bih, n, f) + rdf(bhh, n, f);
  else { int j = n - 2048; bg[n] = rdf(bi2h, j, f) + rdf(bh2h, j, f); }
}

__global__ void xembk(const int* __restrict__ seq, const void* __restrict__ embed,
                      u16* __restrict__ xe, u16* __restrict__ zb,
                      const int* __restrict__ flag){
  const int f = *flag;
  int t = blockIdx.x, b = blockIdx.y, e = threadIdx.x;
  int idx = seq[b*161 + t];
  u16 v = rdb(embed, (size_t)idx*256 + e, f);
  xe[((size_t)t*32 + b)*256 + e] = v;
  if (t == 0) zb[(size_t)b*1280 + e] = v;
}

// CE = relu(cnn@Wce + bce), CW = cnn@Watt   (M=8192, N=1024, K=512)
__global__ __launch_bounds__(256) void ctxgemm(const void* __restrict__ A,
                                               const u16* __restrict__ WT3,
                                               const void* __restrict__ bce,
                                               u16* __restrict__ CE, u16* __restrict__ CW,
                                               const int* __restrict__ flag){
  const int f = *flag;
  int wave = threadIdx.x >> 6, lane = threadIdx.x & 63;
  int job = blockIdx.x*4 + wave;
  int mq = job >> 4, nq = job & 15;
  int m0 = mq*64, n0 = nq*64;
  int lr = lane & 15, lq = lane >> 4;
  f4 acc[4][4] = {};
  for (int ks = 0; ks < 16; ks++){
    int k0 = ks*32 + lq*8;
    s8 a[4], b[4];
    #pragma unroll
    for (int mt = 0; mt < 4; mt++){
      size_t base = (size_t)(m0 + mt*16 + lr)*512 + k0;
      if (f){
        const float4* ap = (const float4*)((const float*)A + base);
        float4 q0 = ap[0], q1 = ap[1];
        union { u16 u[8]; s8 v; } pk;
        pk.u[0]=f2b(q0.x); pk.u[1]=f2b(q0.y); pk.u[2]=f2b(q0.z); pk.u[3]=f2b(q0.w);
        pk.u[4]=f2b(q1.x); pk.u[5]=f2b(q1.y); pk.u[6]=f2b(q1.z); pk.u[7]=f2b(q1.w);
        a[mt] = pk.v;
      } else {
        a[mt] = *(const s8*)((const u16*)A + base);
      }
    }
    #pragma unroll
    for (int nt = 0; nt < 4; nt++) b[nt] = *(const s8*)(WT3 + (size_t)(n0 + nt*16 + lr)*512 + k0);
    #pragma unroll
    for (int mt = 0; mt < 4; mt++)
      #pragma unroll
      for (int nt = 0; nt < 4; nt++)
        acc[mt][nt] = __builtin_amdgcn_mfma_f32_16x16x32_bf16(a[mt], b[nt], acc[mt][nt], 0, 0, 0);
  }
  #pragma unroll
  for (int mt = 0; mt < 4; mt++)
    #pragma unroll
    for (int nt = 0; nt < 4; nt++)
      #pragma unroll
      for (int r = 0; r < 4; r++){
        int row = m0 + mt*16 + lq*4 + r;
        int col = n0 + nt*16 + lr;
        float d = acc[mt][nt][r];
        if (col < 512){ d += rdf(bce, col, f); d = d > 0.f ? d : 0.f; CE[(size_t)row*512 + col] = f2b(d); }
        else CW[(size_t)row*512 + (col - 512)] = f2b(d);
      }
}

// ---------------- persistent step kernel ----------------
struct DP {
  const void *bfr, *bfre, *bho, *bhoe, *Wa, *batt, *blog;
  const u16 *WT1, *WT2, *xe, *CE, *CW, *w45, *w6;
  const float *bg;
  const int *flag;
  u16 *zb, *ab1, *ab2; float *cbuf, *v4;
  float *gp0, *gp1, *lp0, *lp1;
  unsigned *slots, *rel;
  void *out;
};

// NBLK blocks x 256 threads, persistent. Whole t-loop inside.
__global__ __launch_bounds__(256) void loopk(DP p){
  const int blk = blockIdx.x;
  const int tid = threadIdx.x, lane = tid & 63, wv = tid >> 6;
  const int lr = lane & 15, lq = lane >> 4;
  const int f = *p.flag;
  unsigned gen = 0;

  __shared__ float sFRE[512], sHOE[512], sWa[512], sP[257], sRED[256], sV[4][512];
  __shared__ u16 sPK[2048];   // u16 pack-staging (B: 1024, C: 2048, EF: 512)

  for (int t = 0; t <= TT; ++t){
    // ---------------- phase A: gates GEMM (t) + logits GEMM (t-1) ----------------
    {
      const int gwave = blk*4 + wv;
      if (t < TT && gwave < 320){
        const int nt = gwave >> 1, kh = gwave & 1;
        const u16* Bp = p.WT1 + (size_t)(nt*16 + lr)*1280 + kh*640 + lq*8;
        const u16* Ap = p.zb + (size_t)lr*1280 + kh*640 + lq*8;
        f4 a0 = {0,0,0,0}, a1 = {0,0,0,0};
        #pragma unroll 4
        for (int ks = 0; ks < 20; ++ks){
          s8 fa0 = ld128(Ap + ks*32);
          s8 fa1 = ld128(Ap + 16*1280 + ks*32);
          s8 fb  = *(const s8*)(Bp + ks*32);
          a0 = __builtin_amdgcn_mfma_f32_16x16x32_bf16(fa0, fb, a0, 0, 0, 0);
          a1 = __builtin_amdgcn_mfma_f32_16x16x32_bf16(fa1, fb, a1, 0, 0, 0);
        }
        float* gp = kh ? p.gp1 : p.gp0;
        const int col = nt*16 + lr, r0 = lq*4;
        #pragma unroll
        for (int r = 0; r < 4; ++r){
          stf(gp + (size_t)(r0 + r)*2560 + col, a0[r]);
          stf(gp + (size_t)(16 + r0 + r)*2560 + col, a1[r]);
        }
      } else if (t > 0 && gwave >= 320 && gwave < 946){
        const int j = gwave - 320, nt = j >> 1, kh = j & 1;
        const u16* Bp = p.WT2 + (size_t)(nt*16 + lr)*512 + kh*256 + lq*8;
        const u16* Ap = p.zb + 256 + (size_t)lr*1280 + kh*256 + lq*8;
        f4 a0 = {0,0,0,0}, a1 = {0,0,0,0};
        #pragma unroll
        for (int ks = 0; ks < 8; ++ks){
          s8 fa0 = ld128(Ap + ks*32);
          s8 fa1 = ld128(Ap + 16*1280 + ks*32);
          s8 fb  = *(const s8*)(Bp + ks*32);
          a0 = __builtin_amdgcn_mfma_f32_16x16x32_bf16(fa0, fb, a0, 0, 0, 0);
          a1 = __builtin_amdgcn_mfma_f32_16x16x32_bf16(fa1, fb, a1, 0, 0, 0);
        }
        float* lp = kh ? p.lp1 : p.lp0;
        const int col = nt*16 + lr, r0 = lq*4;
        #pragma unroll
        for (int r = 0; r < 4; ++r){
          stf(lp + (size_t)(r0 + r)*5008 + col, a0[r]);
          stf(lp + (size_t)(16 + r0 + r)*5008 + col, a1[r]);
        }
      }
    }
    gbar(p.slots, p.rel, gen);

    // ---------------- phase B: log-softmax(t-1) || LSTM pointwise ----------------
    if (t > 0 && blk < 32){
      const int b = blk;
      const float* l0 = p.lp0 + (size_t)b*5008;
      const float* l1 = p.lp1 + (size_t)b*5008;
      float x[20];
      float m = -3.0e38f;
      #pragma unroll
      for (int i = 0; i < 20; i++){
        int v = tid + i*256;
        x[i] = (v < 5000) ? (ldf(l0 + v) + ldf(l1 + v) + rdf(p.blog, v, f)) : -3.0e38f;
        m = fmaxf(m, x[i]);
      }
      sRED[tid] = m; __syncthreads();
      for (int off = 128; off; off >>= 1){ if (tid < off) sRED[tid] = fmaxf(sRED[tid], sRED[tid+off]); __syncthreads(); }
      float M = sRED[0]; __syncthreads();
      float s = 0.f;
      #pragma unroll
      for (int i = 0; i < 20; i++){ int v = tid + i*256; if (v < 5000) s += __expf(x[i] - M); }
      sRED[tid] = s; __syncthreads();
      for (int off = 128; off; off >>= 1){ if (tid < off) sRED[tid] += sRED[tid+off]; __syncthreads(); }
      float lse = M + __logf(sRED[0]);
      const size_t ob = ((size_t)b*160 + (t-1))*5000;
      if (f){
        float* op = (float*)p.out;
        #pragma unroll
        for (int i = 0; i < 20; i++){ int v = tid + i*256; if (v < 5000) op[ob + v] = x[i] - lse; }
      } else {
        u16* op = (u16*)p.out;
        #pragma unroll
        for (int i = 0; i < 20; i++){ int v = tid + i*256; if (v < 5000) op[ob + v] = f2b(x[i] - lse); }
      }
    } else if (t < TT && blk >= 32 && blk < 64){
      const int b = blk - 32;
      const float* cold = p.cbuf + (size_t)(t & 1)*16384 + (size_t)b*512;
      float*       cnew = p.cbuf + (size_t)((t + 1) & 1)*16384 + (size_t)b*512;
      const float* g0 = p.gp0 + (size_t)b*2560;
      const float* g1 = p.gp1 + (size_t)b*2560;
      #pragma unroll
      for (int i = 0; i < 2; i++){
        const int j = tid + i*256;
        float gi = ldf(g0 + j)        + ldf(g1 + j)        + p.bg[j];
        float gf = ldf(g0 + 512 + j)  + ldf(g1 + 512 + j)  + p.bg[512+j];
        float gg = ldf(g0 + 1024 + j) + ldf(g1 + 1024 + j) + p.bg[1024+j];
        float go = ldf(g0 + 1536 + j) + ldf(g1 + 1536 + j) + p.bg[1536+j];
        float g5 = ldf(g0 + 2048 + j) + ldf(g1 + 2048 + j) + p.bg[2048+j];
        float cn = sigm(gf)*cold[j] + sigm(gi)*tanhp(gg);
        float tc = tanhp(cn);
        float hn = sigm(go)*tc;
        sPK[j]       = f2b(sigm(g5)*tc);   // fr_pre
        sPK[512 + j] = f2b(hn);            // h_n
        cnew[j] = cn;
      }
      __syncthreads();
      // pack to 8B coherent stores: ab1 row b (1024 u16), zb.h (512 u16), xt (256 u16)
      st64(p.ab1 + (size_t)b*1024 + tid*4, *(const u64*)(sPK + tid*4));
      if (tid < 128)
        st64(p.zb + (size_t)b*1280 + 768 + tid*4, *(const u64*)(sPK + 512 + tid*4));
      if (t < TT - 1 && tid < 64){
        u64 q = *(const u64*)(p.xe + ((size_t)(t + 1)*32 + b)*256 + tid*4);
        st64(p.zb + (size_t)b*1280 + tid*4, q);
      }
    }
    if (t == TT) break;
    gbar(p.slots, p.rel, gen);

    // ---------------- phase C: AB2 = act(AB1 @ diag(Wfr,Who) + bias) ----------------
    if (blk < 16){
      const int job = blk*4 + wv;              // 0..63
      const int n0 = job*16;
      const u16* Bp = p.w45 + (size_t)(n0 + lr)*1024 + lq*8;
      const u16* Ap = p.ab1 + (size_t)lr*1024 + lq*8;
      f4 a0 = {0,0,0,0}, a1 = {0,0,0,0};
      #pragma unroll 8
      for (int ks = 0; ks < 32; ++ks){
        s8 fa0 = ld128(Ap + ks*32);
        s8 fa1 = ld128(Ap + 16*1024 + ks*32);
        s8 fb  = *(const s8*)(Bp + ks*32);
        a0 = __builtin_amdgcn_mfma_f32_16x16x32_bf16(fa0, fb, a0, 0, 0, 0);
        a1 = __builtin_amdgcn_mfma_f32_16x16x32_bf16(fa1, fb, a1, 0, 0, 0);
      }
      const int col = n0 + lr, r0 = lq*4;
      const int lcol = wv*16 + lr;             // 0..63 within block's 64-col slab
      #pragma unroll
      for (int r = 0; r < 4; ++r){
        float v0 = a0[r], v1 = a1[r];
        if (col < 512){ float bb = rdf(p.bfr, col, f); v0 = fmaxf(v0 + bb, 0.f); v1 = fmaxf(v1 + bb, 0.f); }
        else          { float bb = rdf(p.bho, col - 512, f); v0 = tanhp(v0 + bb); v1 = tanhp(v1 + bb); }
        sPK[(r0 + r)*64 + lcol]      = f2b(v0);
        sPK[(16 + r0 + r)*64 + lcol] = f2b(v1);
      }
      __syncthreads();
      // repack: rows 0..31 x 64 cols -> 8B coherent stores
      const int row = tid >> 3, c0 = (tid & 7)*8;
      const u16* s = sPK + row*64 + c0;
      u16* dstp = p.ab2 + (size_t)row*1024 + blk*64 + c0;
      st64(dstp,     *(const u64*)s);
      st64(dstp + 4, *(const u64*)(s + 4));
    }
    gbar(p.slots, p.rel, gen);

    // ---------------- phase D: V4 = AB2 @ [Wfre|Whoe|Watt|Watt] ----------------
    if (blk < 32){
      const int job = blk*4 + wv;              // 0..127
      const int n0 = job*16;
      const u16* Bp = p.w6 + (size_t)(n0 + lr)*1024 + lq*8;
      const u16* Ap = p.ab2 + (size_t)lr*1024 + lq*8;
      f4 a0 = {0,0,0,0}, a1 = {0,0,0,0};
      #pragma unroll 8
      for (int ks = 0; ks < 32; ++ks){
        s8 fa0 = ld128(Ap + ks*32);
        s8 fa1 = ld128(Ap + 16*1024 + ks*32);
        s8 fb  = *(const s8*)(Bp + ks*32);
        a0 = __builtin_amdgcn_mfma_f32_16x16x32_bf16(fa0, fb, a0, 0, 0, 0);
        a1 = __builtin_amdgcn_mfma_f32_16x16x32_bf16(fa1, fb, a1, 0, 0, 0);
      }
      const int col = n0 + lr, r0 = lq*4;
      float add = 0.f;
      if (col < 512)        add = rdf(p.bfre, col, f);
      else if (col < 1024)  add = rdf(p.bhoe, col - 512, f);
      #pragma unroll
      for (int r = 0; r < 4; ++r){
        stf(p.v4 + (size_t)(r0 + r)*2048 + col,      a0[r] + add);
        stf(p.v4 + (size_t)(16 + r0 + r)*2048 + col, a1[r] + add);
      }
    }
    gbar(p.slots, p.rel, gen);

    // ---------------- phase EF: scores + softmax + vis + out_h -> zb ----------------
    if (blk < 32){
      const int b = blk;
      const float* v4 = p.v4 + (size_t)b*2048;
      for (int i = tid; i < 512; i += 256){
        sFRE[i] = ldf(v4 + i); sHOE[i] = ldf(v4 + 512 + i); sWa[i] = rdf(p.Wa, i, f);
      }
      __syncthreads();
      // scores over 257 atoms, lane covers 8 h's
      const int h0 = lane*8;
      for (int a = wv; a < 257; a += 4){
        float pp = 0.f;
        if (a == 0){
          #pragma unroll
          for (int j = 0; j < 8; ++j){ int h = h0 + j; pp += tanhp(sFRE[h] + sHOE[h]) * sWa[h]; }
        } else {
          s8 c8 = *(const s8*)(p.CE + ((size_t)b*256 + (a - 1))*512 + h0);
          #pragma unroll
          for (int j = 0; j < 8; ++j){ int h = h0 + j; pp += tanhp(b2f((u16)c8[j]) + sHOE[h]) * sWa[h]; }
        }
        #pragma unroll
        for (int o = 32; o; o >>= 1) pp += __shfl_xor(pp, o, 64);
        if (lane == 0) sP[a] = pp;
      }
      __syncthreads();
      // softmax over 257
      {
        float v0 = sP[tid];
        float v1 = (tid == 0) ? sP[256] : -3.0e38f;
        sRED[tid] = fmaxf(v0, v1); __syncthreads();
        for (int o = 128; o; o >>= 1){ if (tid < o) sRED[tid] = fmaxf(sRED[tid], sRED[tid+o]); __syncthreads(); }
        float M = sRED[0]; __syncthreads();
        float e0 = __expf(v0 - M), e1 = (tid == 0) ? __expf(v1 - M) : 0.f;
        sRED[tid] = e0 + e1; __syncthreads();
        for (int o = 128; o; o >>= 1){ if (tid < o) sRED[tid] += sRED[tid+o]; __syncthreads(); }
        float rS = 1.0f / sRED[0]; __syncthreads();
        sP[tid] = e0 * rS;
        if (tid == 0) sP[256] = e1 * rS;
      }
      __syncthreads();
      // vis partials: wave covers full 512 cols (lane*8), a-split across waves
      {
        float acc[8] = {0,0,0,0,0,0,0,0};
        for (int a = wv; a < 257; a += 4){
          float wgt = sP[a];
          if (a == 0){
            #pragma unroll
            for (int j = 0; j < 8; ++j) acc[j] += wgt * ldf(v4 + 1024 + h0 + j);
          } else {
            s8 c8 = *(const s8*)(p.CW + ((size_t)b*256 + (a - 1))*512 + h0);
            #pragma unroll
            for (int j = 0; j < 8; ++j) acc[j] += wgt * b2f((u16)c8[j]);
          }
        }
        #pragma unroll
        for (int j = 0; j < 8; ++j) sV[wv][h0 + j] = acc[j];
      }
      __syncthreads();
      #pragma unroll
      for (int i = 0; i < 2; ++i){
        int col = tid + i*256;
        float s = sV[0][col] + sV[1][col] + sV[2][col] + sV[3][col]
                + ldf(v4 + 1536 + col) + rdf(p.batt, col, f);
        sPK[col] = f2b(tanhp(s));
      }
      __syncthreads();
      if (tid < 128)
        st64(p.zb + (size_t)b*1280 + 256 + tid*4, *(const u64*)(sPK + tid*4));
    }
    gbar(p.slots, p.rel, gen);
  }
}

// ---------------- host launch ----------------
extern "C" void kernel_launch(void* const* d_in, const int* in_sizes, int n_in,
                              void* d_out, int out_size, void* d_ws, size_t ws_size,
                              hipStream_t stream){
  char* w = (char*)d_ws;
  u16*   ZB  = (u16*)(w + oZB);
  float* CB  = (float*)(w + oC);
  int*   FLAG= (int*)(w + oFLAG);
  u16*   WT1 = (u16*)(w + oWT1);
  u16*   WT2 = (u16*)(w + oWT2);
  u16*   WT3 = (u16*)(w + oWT3);
  float* BG  = (float*)(w + oBG);
  u16*   XE  = (u16*)(w + oXE);
  u16*   CE  = (u16*)(w + oCE);
  u16*   CW  = (u16*)(w + oCW);
  u16*   W45T= (u16*)(w + oW45T);
  u16*   W6T = (u16*)(w + oW6T);

  (void)hipMemsetAsync(w, 0, ZERO_END, stream);                  // zb, c, flag, barrier slots
  (void)hipMemsetAsync(w + oWT2, 0, (size_t)5008*512*2, stream); // WT2 incl. pad
  (void)hipMemsetAsync(w + oW45T, 0, (size_t)(2097152 + 4194304), stream); // W45T+W6T

  const int* seq  = (const int*)d_in[1];

  probek<<<1, 256, 0, stream>>>((const u16*)d_in[0], FLAG);

  auto T = [&](const void* src, u16* dst, int R, int C, int stride){
    tposek<<<dim3((C + 31)/32, (R + 31)/32), 256, 0, stream>>>(src, dst, R, C, stride, FLAG);
  };
  T(d_in[5],  WT1,                              768, 2048, 1280);  // Wih
  T(d_in[7],  WT1 + 768,                        512, 2048, 1280);  // Whh
  T(d_in[9],  WT1 + (size_t)2048*1280,          768,  512, 1280);  // Wi2h
  T(d_in[11], WT1 + (size_t)2048*1280 + 768,    512,  512, 1280);  // Wh2h
  T(d_in[25], WT2,                              512, 5000,  512);  // Wlog
  T(d_in[3],  WT3,                              512,  512,  512);  // Wce
  T(d_in[23], WT3 + (size_t)512*512,            512,  512,  512);  // Watt (ctx)
  T(d_in[13], W45T,                             512,  512, 1024);  // Wfr
  T(d_in[17], W45T + (size_t)512*1024 + 512,    512,  512, 1024);  // Who
  T(d_in[15], W6T,                              512,  512, 1024);  // Wfre
  T(d_in[19], W6T + (size_t)512*1024 + 512,     512,  512, 1024);  // Whoe
  T(d_in[23], W6T + (size_t)1024*1024,          512,  512, 1024);  // Watt (frW)
  T(d_in[23], W6T + (size_t)1536*1024 + 512,    512,  512, 1024);  // Watt (holW)

  biask<<<10, 256, 0, stream>>>(d_in[6], d_in[8], d_in[10], d_in[12], BG, FLAG);
  xembk<<<dim3(160, 32), 256, 0, stream>>>(seq, d_in[2], XE, ZB, FLAG);
  ctxgemm<<<512, 256, 0, stream>>>(d_in[0], WT3, d_in[4], CE, CW, FLAG);

  DP p;
  p.bfr  = d_in[14]; p.bfre = d_in[16];
  p.bho  = d_in[18]; p.bhoe = d_in[20];
  p.Wa   = d_in[21]; p.batt = d_in[24];
  p.blog = d_in[26];
  p.WT1 = WT1; p.WT2 = WT2; p.xe = XE; p.CE = CE; p.CW = CW;
  p.w45 = W45T; p.w6 = W6T;
  p.bg = BG; p.flag = FLAG; p.zb = ZB; p.cbuf = CB;
  p.ab1 = (u16*)(w + oAB1); p.ab2 = (u16*)(w + oAB2);
  p.v4  = (float*)(w + oV4);
  p.gp0 = (float*)(w + oGP0); p.gp1 = (float*)(w + oGP1);
  p.lp0 = (float*)(w + oLP0); p.lp1 = (float*)(w + oLP1);
  p.slots = (unsigned*)(w + oSLOT);
  p.rel   = (unsigned*)(w + oREL);
  p.out = d_out;

  loopk<<<NBLK, 256, 0, stream>>>(p);
}

// Round 5
// 13165.245 us; speedup vs baseline: 2.4541x; 1.7582x over previous
//
#include <hip/hip_runtime.h>

// AdaDecoder — persistent kernel, parallel-split attention (round 11).
// R10 post-mortem: barriers are ~6us, NOT the bottleneck. Phase EF was ~95us/step:
// 64 serial L2-missing CE/CW loads per wave (CE+CW = 16.8MB thrashes 4MB/XCD L2 ->
// FETCH 15MB/step from IC at ~0.7us latency each, on only 32 blocks).
// Fix: flash-style split. EF1 on 224 blocks (7 per batch x ~37 atoms): unnormalized
// exp(score) + vis partials (scores bounded |s|<~8 -> no max pass; softmax is
// shift-invariant -> ba dropped). EF2 on 32 blocks: S=sum s_j, V=sum v_j,
// out=tanh(V/S + holW + batt). Partials live in the dead gp0/gp1 window.
// 6 barriers/step now, but serial-latency chain per wave drops 64 -> ~10 iters.

typedef unsigned short u16;
typedef unsigned long long u64;
typedef __attribute__((ext_vector_type(8))) short s8;
typedef __attribute__((ext_vector_type(4))) float f4;

#define TT 160
#define NBLK 240

// ---------------- ws layout (bytes) ----------------
static constexpr size_t oZB   = 0;              // u16 zb[32][1280]  (xt|out_prev|h)
static constexpr size_t oC    = 81920;          // float c[2][32][512]
static constexpr size_t oFLAG = 212992;         // int dtype flag (1 = fp32 inputs)
static constexpr size_t oSLOT = 213504;         // unsigned slots[240*2] (8B stride)
static constexpr size_t oREL  = 215488;         // unsigned release word (own line)
static constexpr size_t ZERO_END = 217088;
static constexpr size_t oWT1  = 217088;         // u16 [2560][1280]  gates/n5 W^T
static constexpr size_t oWT2  = 6770688;        // u16 [5008][512]   Wlog^T (padded)
static constexpr size_t oWT3  = 11898880;       // u16 [1024][512]   [Wce^T | Watt^T]
static constexpr size_t oBG   = 12947456;       // float bg[2560]
static constexpr size_t oXE   = 12957696;       // u16 xemb[160][32][256]
static constexpr size_t oCE   = 15579136;       // u16 CE[32][256][512]
static constexpr size_t oCW   = 23967744;       // u16 CW[32][256][512]
static constexpr size_t oGP0  = 32356352;       // float gp0[32][2560]   (also vP/mS scratch)
static constexpr size_t oGP1  = 32684032;
static constexpr size_t oLP0  = 33011712;       // float lp0[32][5008]
static constexpr size_t oLP1  = 33652736;       // end 34293760
static constexpr size_t oAB1  = 34293760;       // u16 [32][1024]  [fr_pre|h]
static constexpr size_t oAB2  = 34359296;       // u16 [32][1024]  [fr|hol]
static constexpr size_t oV4   = 34424832;       // float [32][2048] [fre|hoe|frW|holW]
static constexpr size_t oW45T = 34686976;       // u16 [1024][1024] diag(Wfr^T,Who^T)
static constexpr size_t oW6T  = 36784128;       // u16 [2048][1024] big B^T
                                                // end 40978432

__device__ __forceinline__ float b2f(u16 u){ return __uint_as_float(((unsigned)u) << 16); }
__device__ __forceinline__ u16 f2b(float f){
  unsigned x = __float_as_uint(f);
  return (u16)((x + 0x7fffu + ((x >> 16) & 1u)) >> 16);
}
__device__ __forceinline__ float sigm(float x){ return 1.0f/(1.0f + __expf(-x)); }
__device__ __forceinline__ float tanhp(float x){ return 1.0f - 2.0f/(__expf(2.0f*x) + 1.0f); }
__device__ __forceinline__ u16 rdb(const void* p, size_t i, int f){
  return f ? f2b(((const float*)p)[i]) : ((const u16*)p)[i];
}
__device__ __forceinline__ float rdf(const void* p, size_t i, int f){
  return f ? ((const float*)p)[i] : b2f(((const u16*)p)[i]);
}

// ---- coherent (L2-bypass) accessors: relaxed agent-scope atomics ----
__device__ __forceinline__ float ldf(const float* p){
  return __hip_atomic_load((float*)p, __ATOMIC_RELAXED, __HIP_MEMORY_SCOPE_AGENT);
}
__device__ __forceinline__ void stf(float* p, float v){
  __hip_atomic_store(p, v, __ATOMIC_RELAXED, __HIP_MEMORY_SCOPE_AGENT);
}
__device__ __forceinline__ u64 ld64(const void* p){
  return __hip_atomic_load((u64*)p, __ATOMIC_RELAXED, __HIP_MEMORY_SCOPE_AGENT);
}
__device__ __forceinline__ void st64(void* p, u64 v){
  __hip_atomic_store((u64*)p, v, __ATOMIC_RELAXED, __HIP_MEMORY_SCOPE_AGENT);
}
__device__ __forceinline__ s8 ld128(const void* p){
  union { u64 q[2]; s8 v; } u;
  u.q[0] = ld64(p);
  u.q[1] = ld64((const char*)p + 8);
  return u.v;
}

// Distributed arrive/release grid barrier (no RMW, no fences). ~6us measured.
__device__ __forceinline__ void gbar(unsigned* slots, unsigned* rel, unsigned& gen){
  ++gen;                                   // uniform across all threads
  __syncthreads();
  asm volatile("s_waitcnt vmcnt(0)" ::: "memory");
  if (blockIdx.x == 0){
    const int tid = threadIdx.x;
    if (tid > 0 && tid < NBLK){
      while (__hip_atomic_load(slots + tid*2, __ATOMIC_RELAXED, __HIP_MEMORY_SCOPE_AGENT) < gen)
        __builtin_amdgcn_s_sleep(1);
    }
    __syncthreads();
    if (tid == 0)
      __hip_atomic_store(rel, gen, __ATOMIC_RELAXED, __HIP_MEMORY_SCOPE_AGENT);
  } else {
    if (threadIdx.x == 0){
      __hip_atomic_store(slots + blockIdx.x*2, gen, __ATOMIC_RELAXED, __HIP_MEMORY_SCOPE_AGENT);
      while (__hip_atomic_load(rel, __ATOMIC_RELAXED, __HIP_MEMORY_SCOPE_AGENT) < gen)
        __builtin_amdgcn_s_sleep(1);
    }
    __syncthreads();
  }
}

// ---------------- probe: detect input dtype ----------------
__global__ void probek(const u16* __restrict__ a, int* flag){
  __shared__ int s[256];
  int t = threadIdx.x;
  float v = fabsf(b2f(a[t]));
  s[t] = (v < 64.0f) ? 0 : 1;
  __syncthreads();
  for (int o = 128; o; o >>= 1){ if (t < o) s[t] += s[t+o]; __syncthreads(); }
  if (t == 0) *flag = (s[0] > 0) ? 1 : 0;
}

// ---------------- preamble kernels ----------------
// dst[n*stride + k] = src[k*C + n]
__global__ void tposek(const void* __restrict__ src, u16* __restrict__ dst,
                       int R, int C, int stride, const int* __restrict__ flag){
  __shared__ u16 tl[32][33];
  const int f = *flag;
  int nt = blockIdx.x*32, kt = blockIdx.y*32;
  int tx = threadIdx.x & 31, ty = threadIdx.x >> 5;
  #pragma unroll
  for (int i = 0; i < 4; i++){
    int k = kt + ty + i*8, n = nt + tx;
    tl[ty + i*8][tx] = (k < R && n < C) ? rdb(src, (size_t)k*C + n, f) : (u16)0;
  }
  __syncthreads();
  #pragma unroll
  for (int i = 0; i < 4; i++){
    int n = nt + ty + i*8, k = kt + tx;
    if (n < C && k < R) dst[(size_t)n*stride + k] = tl[tx][ty + i*8];
  }
}

__global__ void biask(const void* bih, const void* bhh, const void* bi2h, const void* bh2h,
                      float* bg, const int* __restrict__ flag){
  const int f = *flag;
  int n = blockIdx.x*256 + threadIdx.x;
  if (n >= 2560) return;
  if (n < 2048) bg[n] = rdf(bih, n, f) + rdf(bhh, n, f);
  else { int j = n - 2048; bg[n] = rdf(bi2h, j, f) + rdf(bh2h, j, f); }
}

__global__ void xembk(const int* __restrict__ seq, const void* __restrict__ embed,
                      u16* __restrict__ xe, u16* __restrict__ zb,
                      const int* __restrict__ flag){
  const int f = *flag;
  int t = blockIdx.x, b = blockIdx.y, e = threadIdx.x;
  int idx = seq[b*161 + t];
  u16 v = rdb(embed, (size_t)idx*256 + e, f);
  xe[((size_t)t*32 + b)*256 + e] = v;
  if (t == 0) zb[(size_t)b*1280 + e] = v;
}

// CE = relu(cnn@Wce + bce), CW = cnn@Watt   (M=8192, N=1024, K=512)
__global__ __launch_bounds__(256) void ctxgemm(const void* __restrict__ A,
                                               const u16* __restrict__ WT3,
                                               const void* __restrict__ bce,
                                               u16* __restrict__ CE, u16* __restrict__ CW,
                                               const int* __restrict__ flag){
  const int f = *flag;
  int wave = threadIdx.x >> 6, lane = threadIdx.x & 63;
  int job = blockIdx.x*4 + wave;
  int mq = job >> 4, nq = job & 15;
  int m0 = mq*64, n0 = nq*64;
  int lr = lane & 15, lq = lane >> 4;
  f4 acc[4][4] = {};
  for (int ks = 0; ks < 16; ks++){
    int k0 = ks*32 + lq*8;
    s8 a[4], b[4];
    #pragma unroll
    for (int mt = 0; mt < 4; mt++){
      size_t base = (size_t)(m0 + mt*16 + lr)*512 + k0;
      if (f){
        const float4* ap = (const float4*)((const float*)A + base);
        float4 q0 = ap[0], q1 = ap[1];
        union { u16 u[8]; s8 v; } pk;
        pk.u[0]=f2b(q0.x); pk.u[1]=f2b(q0.y); pk.u[2]=f2b(q0.z); pk.u[3]=f2b(q0.w);
        pk.u[4]=f2b(q1.x); pk.u[5]=f2b(q1.y); pk.u[6]=f2b(q1.z); pk.u[7]=f2b(q1.w);
        a[mt] = pk.v;
      } else {
        a[mt] = *(const s8*)((const u16*)A + base);
      }
    }
    #pragma unroll
    for (int nt = 0; nt < 4; nt++) b[nt] = *(const s8*)(WT3 + (size_t)(n0 + nt*16 + lr)*512 + k0);
    #pragma unroll
    for (int mt = 0; mt < 4; mt++)
      #pragma unroll
      for (int nt = 0; nt < 4; nt++)
        acc[mt][nt] = __builtin_amdgcn_mfma_f32_16x16x32_bf16(a[mt], b[nt], acc[mt][nt], 0, 0, 0);
  }
  #pragma unroll
  for (int mt = 0; mt < 4; mt++)
    #pragma unroll
    for (int nt = 0; nt < 4; nt++)
      #pragma unroll
      for (int r = 0; r < 4; r++){
        int row = m0 + mt*16 + lq*4 + r;
        int col = n0 + nt*16 + lr;
        float d = acc[mt][nt][r];
        if (col < 512){ d += rdf(bce, col, f); d = d > 0.f ? d : 0.f; CE[(size_t)row*512 + col] = f2b(d); }
        else CW[(size_t)row*512 + (col - 512)] = f2b(d);
      }
}

// ---------------- persistent step kernel ----------------
struct DP {
  const void *bfr, *bfre, *bho, *bhoe, *Wa, *batt, *blog;
  const u16 *WT1, *WT2, *xe, *CE, *CW, *w45, *w6;
  const float *bg;
  const int *flag;
  u16 *zb, *ab1, *ab2; float *cbuf, *v4;
  float *gp0, *gp1, *lp0, *lp1;
  float *vp, *ms;                 // attention partials (alias gp region)
  unsigned *slots, *rel;
  void *out;
};

// NBLK blocks x 256 threads, persistent. Whole t-loop inside.
__global__ __launch_bounds__(256) void loopk(DP p){
  const int blk = blockIdx.x;
  const int tid = threadIdx.x, lane = tid & 63, wv = tid >> 6;
  const int lr = lane & 15, lq = lane >> 4;
  const int f = *p.flag;
  unsigned gen = 0;

  __shared__ float sHOE[512], sWa[512], sP[64], sRED[256], sV[4][512];
  __shared__ u16 sPK[2048];   // u16 pack-staging

  for (int t = 0; t <= TT; ++t){
    // ---------------- phase A: gates GEMM (t) + logits GEMM (t-1) ----------------
    {
      const int gwave = blk*4 + wv;
      if (t < TT && gwave < 320){
        const int nt = gwave >> 1, kh = gwave & 1;
        const u16* Bp = p.WT1 + (size_t)(nt*16 + lr)*1280 + kh*640 + lq*8;
        const u16* Ap = p.zb + (size_t)lr*1280 + kh*640 + lq*8;
        f4 a0 = {0,0,0,0}, a1 = {0,0,0,0};
        #pragma unroll 4
        for (int ks = 0; ks < 20; ++ks){
          s8 fa0 = ld128(Ap + ks*32);
          s8 fa1 = ld128(Ap + 16*1280 + ks*32);
          s8 fb  = *(const s8*)(Bp + ks*32);
          a0 = __builtin_amdgcn_mfma_f32_16x16x32_bf16(fa0, fb, a0, 0, 0, 0);
          a1 = __builtin_amdgcn_mfma_f32_16x16x32_bf16(fa1, fb, a1, 0, 0, 0);
        }
        float* gp = kh ? p.gp1 : p.gp0;
        const int col = nt*16 + lr, r0 = lq*4;
        #pragma unroll
        for (int r = 0; r < 4; ++r){
          stf(gp + (size_t)(r0 + r)*2560 + col, a0[r]);
          stf(gp + (size_t)(16 + r0 + r)*2560 + col, a1[r]);
        }
      } else if (t > 0 && gwave >= 320 && gwave < 946){
        const int j = gwave - 320, nt = j >> 1, kh = j & 1;
        const u16* Bp = p.WT2 + (size_t)(nt*16 + lr)*512 + kh*256 + lq*8;
        const u16* Ap = p.zb + 256 + (size_t)lr*1280 + kh*256 + lq*8;
        f4 a0 = {0,0,0,0}, a1 = {0,0,0,0};
        #pragma unroll
        for (int ks = 0; ks < 8; ++ks){
          s8 fa0 = ld128(Ap + ks*32);
          s8 fa1 = ld128(Ap + 16*1280 + ks*32);
          s8 fb  = *(const s8*)(Bp + ks*32);
          a0 = __builtin_amdgcn_mfma_f32_16x16x32_bf16(fa0, fb, a0, 0, 0, 0);
          a1 = __builtin_amdgcn_mfma_f32_16x16x32_bf16(fa1, fb, a1, 0, 0, 0);
        }
        float* lp = kh ? p.lp1 : p.lp0;
        const int col = nt*16 + lr, r0 = lq*4;
        #pragma unroll
        for (int r = 0; r < 4; ++r){
          stf(lp + (size_t)(r0 + r)*5008 + col, a0[r]);
          stf(lp + (size_t)(16 + r0 + r)*5008 + col, a1[r]);
        }
      }
    }
    gbar(p.slots, p.rel, gen);

    // ---------------- phase B: log-softmax(t-1) || LSTM pointwise ----------------
    if (t > 0 && blk < 32){
      const int b = blk;
      const float* l0 = p.lp0 + (size_t)b*5008;
      const float* l1 = p.lp1 + (size_t)b*5008;
      float x[20];
      float m = -3.0e38f;
      #pragma unroll
      for (int i = 0; i < 20; i++){
        int v = tid + i*256;
        x[i] = (v < 5000) ? (ldf(l0 + v) + ldf(l1 + v) + rdf(p.blog, v, f)) : -3.0e38f;
        m = fmaxf(m, x[i]);
      }
      sRED[tid] = m; __syncthreads();
      for (int off = 128; off; off >>= 1){ if (tid < off) sRED[tid] = fmaxf(sRED[tid], sRED[tid+off]); __syncthreads(); }
      float M = sRED[0]; __syncthreads();
      float s = 0.f;
      #pragma unroll
      for (int i = 0; i < 20; i++){ int v = tid + i*256; if (v < 5000) s += __expf(x[i] - M); }
      sRED[tid] = s; __syncthreads();
      for (int off = 128; off; off >>= 1){ if (tid < off) sRED[tid] += sRED[tid+off]; __syncthreads(); }
      float lse = M + __logf(sRED[0]);
      const size_t ob = ((size_t)b*160 + (t-1))*5000;
      if (f){
        float* op = (float*)p.out;
        #pragma unroll
        for (int i = 0; i < 20; i++){ int v = tid + i*256; if (v < 5000) op[ob + v] = x[i] - lse; }
      } else {
        u16* op = (u16*)p.out;
        #pragma unroll
        for (int i = 0; i < 20; i++){ int v = tid + i*256; if (v < 5000) op[ob + v] = f2b(x[i] - lse); }
      }
    } else if (t < TT && blk >= 32 && blk < 64){
      const int b = blk - 32;
      const float* cold = p.cbuf + (size_t)(t & 1)*16384 + (size_t)b*512;
      float*       cnew = p.cbuf + (size_t)((t + 1) & 1)*16384 + (size_t)b*512;
      const float* g0 = p.gp0 + (size_t)b*2560;
      const float* g1 = p.gp1 + (size_t)b*2560;
      #pragma unroll
      for (int i = 0; i < 2; i++){
        const int j = tid + i*256;
        float gi = ldf(g0 + j)        + ldf(g1 + j)        + p.bg[j];
        float gf = ldf(g0 + 512 + j)  + ldf(g1 + 512 + j)  + p.bg[512+j];
        float gg = ldf(g0 + 1024 + j) + ldf(g1 + 1024 + j) + p.bg[1024+j];
        float go = ldf(g0 + 1536 + j) + ldf(g1 + 1536 + j) + p.bg[1536+j];
        float g5 = ldf(g0 + 2048 + j) + ldf(g1 + 2048 + j) + p.bg[2048+j];
        float cn = sigm(gf)*cold[j] + sigm(gi)*tanhp(gg);
        float tc = tanhp(cn);
        float hn = sigm(go)*tc;
        sPK[j]       = f2b(sigm(g5)*tc);   // fr_pre
        sPK[512 + j] = f2b(hn);            // h_n
        cnew[j] = cn;
      }
      __syncthreads();
      // pack to 8B coherent stores: ab1 row b (1024 u16), zb.h (512 u16), xt (256 u16)
      st64(p.ab1 + (size_t)b*1024 + tid*4, *(const u64*)(sPK + tid*4));
      if (tid < 128)
        st64(p.zb + (size_t)b*1280 + 768 + tid*4, *(const u64*)(sPK + 512 + tid*4));
      if (t < TT - 1 && tid < 64){
        u64 q = *(const u64*)(p.xe + ((size_t)(t + 1)*32 + b)*256 + tid*4);
        st64(p.zb + (size_t)b*1280 + tid*4, q);
      }
    }
    if (t == TT) break;
    gbar(p.slots, p.rel, gen);

    // ---------------- phase C: AB2 = act(AB1 @ diag(Wfr,Who) + bias) ----------------
    if (blk < 16){
      const int job = blk*4 + wv;              // 0..63
      const int n0 = job*16;
      const u16* Bp = p.w45 + (size_t)(n0 + lr)*1024 + lq*8;
      const u16* Ap = p.ab1 + (size_t)lr*1024 + lq*8;
      f4 a0 = {0,0,0,0}, a1 = {0,0,0,0};
      #pragma unroll 8
      for (int ks = 0; ks < 32; ++ks){
        s8 fa0 = ld128(Ap + ks*32);
        s8 fa1 = ld128(Ap + 16*1024 + ks*32);
        s8 fb  = *(const s8*)(Bp + ks*32);
        a0 = __builtin_amdgcn_mfma_f32_16x16x32_bf16(fa0, fb, a0, 0, 0, 0);
        a1 = __builtin_amdgcn_mfma_f32_16x16x32_bf16(fa1, fb, a1, 0, 0, 0);
      }
      const int col = n0 + lr, r0 = lq*4;
      const int lcol = wv*16 + lr;             // 0..63 within block's 64-col slab
      #pragma unroll
      for (int r = 0; r < 4; ++r){
        float v0 = a0[r], v1 = a1[r];
        if (col < 512){ float bb = rdf(p.bfr, col, f); v0 = fmaxf(v0 + bb, 0.f); v1 = fmaxf(v1 + bb, 0.f); }
        else          { float bb = rdf(p.bho, col - 512, f); v0 = tanhp(v0 + bb); v1 = tanhp(v1 + bb); }
        sPK[(r0 + r)*64 + lcol]      = f2b(v0);
        sPK[(16 + r0 + r)*64 + lcol] = f2b(v1);
      }
      __syncthreads();
      // repack: rows 0..31 x 64 cols -> 8B coherent stores
      const int row = tid >> 3, c0 = (tid & 7)*8;
      const u16* s = sPK + row*64 + c0;
      u16* dstp = p.ab2 + (size_t)row*1024 + blk*64 + c0;
      st64(dstp,     *(const u64*)s);
      st64(dstp + 4, *(const u64*)(s + 4));
    }
    gbar(p.slots, p.rel, gen);

    // ---------------- phase D: V4 = AB2 @ [Wfre|Whoe|Watt|Watt] ----------------
    if (blk < 32){
      const int job = blk*4 + wv;              // 0..127
      const int n0 = job*16;
      const u16* Bp = p.w6 + (size_t)(n0 + lr)*1024 + lq*8;
      const u16* Ap = p.ab2 + (size_t)lr*1024 + lq*8;
      f4 a0 = {0,0,0,0}, a1 = {0,0,0,0};
      #pragma unroll 8
      for (int ks = 0; ks < 32; ++ks){
        s8 fa0 = ld128(Ap + ks*32);
        s8 fa1 = ld128(Ap + 16*1024 + ks*32);
        s8 fb  = *(const s8*)(Bp + ks*32);
        a0 = __builtin_amdgcn_mfma_f32_16x16x32_bf16(fa0, fb, a0, 0, 0, 0);
        a1 = __builtin_amdgcn_mfma_f32_16x16x32_bf16(fa1, fb, a1, 0, 0, 0);
      }
      const int col = n0 + lr, r0 = lq*4;
      float add = 0.f;
      if (col < 512)        add = rdf(p.bfre, col, f);
      else if (col < 1024)  add = rdf(p.bhoe, col - 512, f);
      #pragma unroll
      for (int r = 0; r < 4; ++r){
        stf(p.v4 + (size_t)(r0 + r)*2048 + col,      a0[r] + add);
        stf(p.v4 + (size_t)(16 + r0 + r)*2048 + col, a1[r] + add);
      }
    }
    gbar(p.slots, p.rel, gen);

    // ---------------- phase EF1: partial scores+vis on 224 blocks ----------------
    // block = b*7 + j; atoms [j*37, min(j*37+37,257)). Unnormalized exp (|score|<~8).
    if (blk < 224){
      const int b = blk / 7, jj = blk % 7;
      const int a0 = jj*37;
      const int a1 = (a0 + 37 < 257) ? (a0 + 37) : 257;
      const float* v4 = p.v4 + (size_t)b*2048;
      for (int i = tid; i < 512; i += 256){
        sHOE[i] = ldf(v4 + 512 + i); sWa[i] = rdf(p.Wa, i, f);
      }
      __syncthreads();
      const int h0 = lane*8;
      // scores -> sP[a-a0] = exp(score)
      #pragma unroll 2
      for (int a = a0 + wv; a < a1; a += 4){
        float pp = 0.f;
        if (a == 0){
          #pragma unroll
          for (int j8 = 0; j8 < 8; ++j8){ int h = h0 + j8; pp += tanhp(ldf(v4 + h) + sHOE[h]) * sWa[h]; }
        } else {
          s8 c8 = *(const s8*)(p.CE + ((size_t)b*256 + (a - 1))*512 + h0);
          #pragma unroll
          for (int j8 = 0; j8 < 8; ++j8){ int h = h0 + j8; pp += tanhp(b2f((u16)c8[j8]) + sHOE[h]) * sWa[h]; }
        }
        #pragma unroll
        for (int o = 32; o; o >>= 1) pp += __shfl_xor(pp, o, 64);
        if (lane == 0) sP[a - a0] = __expf(pp);
      }
      __syncthreads();
      // vis partials over this chunk's atoms
      {
        float acc[8] = {0,0,0,0,0,0,0,0};
        #pragma unroll 2
        for (int a = a0 + wv; a < a1; a += 4){
          float wgt = sP[a - a0];
          if (a == 0){
            #pragma unroll
            for (int j8 = 0; j8 < 8; ++j8) acc[j8] += wgt * ldf(v4 + 1024 + h0 + j8);
          } else {
            s8 c8 = *(const s8*)(p.CW + ((size_t)b*256 + (a - 1))*512 + h0);
            #pragma unroll
            for (int j8 = 0; j8 < 8; ++j8) acc[j8] += wgt * b2f((u16)c8[j8]);
          }
        }
        #pragma unroll
        for (int j8 = 0; j8 < 8; ++j8) sV[wv][h0 + j8] = acc[j8];
      }
      __syncthreads();
      // write partial v (512 f32) and s (1 f32)
      #pragma unroll
      for (int i = 0; i < 2; ++i){
        int col = tid + i*256;
        stf(p.vp + ((size_t)b*7 + jj)*512 + col,
            sV[0][col] + sV[1][col] + sV[2][col] + sV[3][col]);
      }
      if (tid == 0){
        float s = 0.f;
        for (int k = 0; k < a1 - a0; ++k) s += sP[k];
        stf(p.ms + b*7 + jj, s);
      }
    }
    gbar(p.slots, p.rel, gen);

    // ---------------- phase EF2: combine -> out_h -> zb ----------------
    if (blk < 32){
      const int b = blk;
      const float* v4 = p.v4 + (size_t)b*2048;
      float S = 0.f;
      #pragma unroll
      for (int k = 0; k < 7; ++k) S += ldf(p.ms + b*7 + k);
      float rS = 1.0f / S;
      #pragma unroll
      for (int i = 0; i < 2; ++i){
        int col = tid + i*256;
        float V = 0.f;
        #pragma unroll
        for (int k = 0; k < 7; ++k) V += ldf(p.vp + ((size_t)b*7 + k)*512 + col);
        float s = V*rS + ldf(v4 + 1536 + col) + rdf(p.batt, col, f);
        sPK[col] = f2b(tanhp(s));
      }
      __syncthreads();
      if (tid < 128)
        st64(p.zb + (size_t)b*1280 + 256 + tid*4, *(const u64*)(sPK + tid*4));
    }
    gbar(p.slots, p.rel, gen);
  }
}

// ---------------- host launch ----------------
extern "C" void kernel_launch(void* const* d_in, const int* in_sizes, int n_in,
                              void* d_out, int out_size, void* d_ws, size_t ws_size,
                              hipStream_t stream){
  char* w = (char*)d_ws;
  u16*   ZB  = (u16*)(w + oZB);
  float* CB  = (float*)(w + oC);
  int*   FLAG= (int*)(w + oFLAG);
  u16*   WT1 = (u16*)(w + oWT1);
  u16*   WT2 = (u16*)(w + oWT2);
  u16*   WT3 = (u16*)(w + oWT3);
  float* BG  = (float*)(w + oBG);
  u16*   XE  = (u16*)(w + oXE);
  u16*   CE  = (u16*)(w + oCE);
  u16*   CW  = (u16*)(w + oCW);
  u16*   W45T= (u16*)(w + oW45T);
  u16*   W6T = (u16*)(w + oW6T);

  (void)hipMemsetAsync(w, 0, ZERO_END, stream);                  // zb, c, flag, barrier slots
  (void)hipMemsetAsync(w + oWT2, 0, (size_t)5008*512*2, stream); // WT2 incl. pad
  (void)hipMemsetAsync(w + oW45T, 0, (size_t)(2097152 + 4194304), stream); // W45T+W6T

  const int* seq  = (const int*)d_in[1];

  probek<<<1, 256, 0, stream>>>((const u16*)d_in[0], FLAG);

  auto T = [&](const void* src, u16* dst, int R, int C, int stride){
    tposek<<<dim3((C + 31)/32, (R + 31)/32), 256, 0, stream>>>(src, dst, R, C, stride, FLAG);
  };
  T(d_in[5],  WT1,                              768, 2048, 1280);  // Wih
  T(d_in[7],  WT1 + 768,                        512, 2048, 1280);  // Whh
  T(d_in[9],  WT1 + (size_t)2048*1280,          768,  512, 1280);  // Wi2h
  T(d_in[11], WT1 + (size_t)2048*1280 + 768,    512,  512, 1280);  // Wh2h
  T(d_in[25], WT2,                              512, 5000,  512);  // Wlog
  T(d_in[3],  WT3,                              512,  512,  512);  // Wce
  T(d_in[23], WT3 + (size_t)512*512,            512,  512,  512);  // Watt (ctx)
  T(d_in[13], W45T,                             512,  512, 1024);  // Wfr
  T(d_in[17], W45T + (size_t)512*1024 + 512,    512,  512, 1024);  // Who
  T(d_in[15], W6T,                              512,  512, 1024);  // Wfre
  T(d_in[19], W6T + (size_t)512*1024 + 512,     512,  512, 1024);  // Whoe
  T(d_in[23], W6T + (size_t)1024*1024,          512,  512, 1024);  // Watt (frW)
  T(d_in[23], W6T + (size_t)1536*1024 + 512,    512,  512, 1024);  // Watt (holW)

  biask<<<10, 256, 0, stream>>>(d_in[6], d_in[8], d_in[10], d_in[12], BG, FLAG);
  xembk<<<dim3(160, 32), 256, 0, stream>>>(seq, d_in[2], XE, ZB, FLAG);
  ctxgemm<<<512, 256, 0, stream>>>(d_in[0], WT3, d_in[4], CE, CW, FLAG);

  DP p;
  p.bfr  = d_in[14]; p.bfre = d_in[16];
  p.bho  = d_in[18]; p.bhoe = d_in[20];
  p.Wa   = d_in[21]; p.batt = d_in[24];
  p.blog = d_in[26];
  p.WT1 = WT1; p.WT2 = WT2; p.xe = XE; p.CE = CE; p.CW = CW;
  p.w45 = W45T; p.w6 = W6T;
  p.bg = BG; p.flag = FLAG; p.zb = ZB; p.cbuf = CB;
  p.ab1 = (u16*)(w + oAB1); p.ab2 = (u16*)(w + oAB2);
  p.v4  = (float*)(w + oV4);
  p.gp0 = (float*)(w + oGP0); p.gp1 = (float*)(w + oGP1);
  p.lp0 = (float*)(w + oLP0); p.lp1 = (float*)(w + oLP1);
  p.vp  = (float*)(w + oGP0);            // 32*7*512 f32 = 458752B (dead gp window)
  p.ms  = (float*)(w + oGP0 + 458752);   // 32*7 f32
  p.slots = (unsigned*)(w + oSLOT);
  p.rel   = (unsigned*)(w + oREL);
  p.out = d_out;

  loopk<<<NBLK, 256, 0, stream>>>(p);
}